// Round 3
// baseline (420.688 us; speedup 1.0000x reference)
//
#include <hip/hip_runtime.h>

// ---------------------------------------------------------------------------
// LatentMixtureAllRNNAgent: fused per-agent fc1 -> GRU cell -> fc2 on MI355X.
// Round 3: same numerics as round 2 (split-bf16 fc1, centered gate weights +
// exact rowsum correction), but gate phase restructured per 16-col subtile to
// cut peak live registers ~4x and eliminate VGPR spill-to-scratch traffic
// (round 2: VGPR_Count=128 with ~250 live -> 388 MB scratch writes).
// ---------------------------------------------------------------------------

typedef __attribute__((ext_vector_type(4))) float f32x4;
typedef __attribute__((ext_vector_type(8))) short s8;     // 8 bf16 (4 VGPRs)
typedef __attribute__((ext_vector_type(4))) unsigned short us4;

#define QSIZE   983040      /* 32768*30 */
#define W1H_OFF 0
#define W1L_OFF 524288
#define WIH_OFF 1048576
#define WHH_OFF 2621440
#define W2T_OFF 4194304

static __device__ __forceinline__ unsigned short f2bf(float f) {
  union { float f; unsigned u; } v; v.f = f;
  unsigned r = v.u + 0x7FFFu + ((v.u >> 16) & 1u);   // RNE
  return (unsigned short)(r >> 16);
}
static __device__ __forceinline__ float bf2f(unsigned short u) {
  union { unsigned u; float f; } v; v.u = ((unsigned)u) << 16;
  return v.f;
}
static __device__ __forceinline__ float sigm(float x) {
  return 1.0f / (1.0f + __expf(-x));
}
static __device__ __forceinline__ float tanh_(float x) {
  return 1.0f - 2.0f / (__expf(2.0f * x) + 1.0f);    // saturates correctly
}

// ------------- prep: f32 [a][k][n] -> bf16 [a][n][k] planes in ws -----------
__global__ void prep_weights(const float* __restrict__ fc1w,
                             const float* __restrict__ rihw,
                             const float* __restrict__ rhhw,
                             const float* __restrict__ fc2w,
                             unsigned short* __restrict__ ws) {
  int q = blockIdx.x * 256 + threadIdx.x;   // one us4 (4 k-values) per thread
  if (q < 131072) {                         // fc1: hi + lo planes
    int a = q >> 14, rem = q & 16383, k4 = rem >> 8, n = rem & 255;
    const float* s = fc1w + a * 65536 + (k4 * 4) * 256 + n;
    float v0 = s[0], v1 = s[256], v2 = s[512], v3 = s[768];
    us4 hi = { f2bf(v0), f2bf(v1), f2bf(v2), f2bf(v3) };
    us4 lo = { f2bf(v0 - bf2f(hi[0])), f2bf(v1 - bf2f(hi[1])),
               f2bf(v2 - bf2f(hi[2])), f2bf(v3 - bf2f(hi[3])) };
    int o = ((a * 256 + n) << 8) + k4 * 4;
    *(us4*)(ws + W1H_OFF + o) = hi;
    *(us4*)(ws + W1L_OFF + o) = lo;
  } else if (q < 524288) {                  // rnn_ih, centered (w - 0.5)
    int t = q - 131072;
    int a = t / 49152, rem = t % 49152, k4 = rem / 768, n = rem % 768;
    const float* s = rihw + a * 196608 + (k4 * 4) * 768 + n;
    us4 v = { f2bf(s[0] - 0.5f), f2bf(s[768] - 0.5f),
              f2bf(s[1536] - 0.5f), f2bf(s[2304] - 0.5f) };
    *(us4*)(ws + WIH_OFF + ((a * 768 + n) << 8) + k4 * 4) = v;
  } else if (q < 917504) {                  // rnn_hh, centered
    int t = q - 524288;
    int a = t / 49152, rem = t % 49152, k4 = rem / 768, n = rem % 768;
    const float* s = rhhw + a * 196608 + (k4 * 4) * 768 + n;
    us4 v = { f2bf(s[0] - 0.5f), f2bf(s[768] - 0.5f),
              f2bf(s[1536] - 0.5f), f2bf(s[2304] - 0.5f) };
    *(us4*)(ws + WHH_OFF + ((a * 768 + n) << 8) + k4 * 4) = v;
  } else if (q < 933888) {                  // fc2: plain, pad 30->32
    int t = q - 917504;
    int a = t >> 11, rem = t & 2047, k4 = rem >> 5, n = rem & 31;
    us4 v = { 0, 0, 0, 0 };
    if (n < 30) {
      const float* s = fc2w + a * 7680 + (k4 * 4) * 30 + n;
      v = (us4){ f2bf(s[0]), f2bf(s[30]), f2bf(s[60]), f2bf(s[90]) };
    }
    *(us4*)(ws + W2T_OFF + ((a * 32 + n) << 8) + k4 * 4) = v;
  }
}

// ------- stage 64x256 f32 tile -> split bf16 (hi plane p0, lo plane p1) -----
static __device__ __forceinline__ void stage_split(unsigned short* p0,
                                                   unsigned short* p1,
                                                   const float* __restrict__ src,
                                                   int rowbase, int a, int tid) {
#pragma unroll
  for (int k = 0; k < 16; ++k) {
    int j = tid + k * 256;
    int r = j >> 6;
    int c4 = (j & 63) << 2;
    const float* p = src + ((((rowbase + r) << 3) + a) << 8) + c4;
    float4 v = *(const float4*)p;
    us4 hi = { f2bf(v.x), f2bf(v.y), f2bf(v.z), f2bf(v.w) };
    us4 lo = { f2bf(v.x - bf2f(hi[0])), f2bf(v.y - bf2f(hi[1])),
               f2bf(v.z - bf2f(hi[2])), f2bf(v.w - bf2f(hi[3])) };
    int idx = ((r << 8) + c4) ^ ((r & 7) << 3);   // XOR swizzle (16B blocks)
    *(us4*)(p0 + idx) = hi;
    *(us4*)(p1 + idx) = lo;
  }
}

// ------------- stage 64x256 f32 tile -> single bf16 plane -------------------
static __device__ __forceinline__ void stage_single(unsigned short* p,
                                                    const float* __restrict__ src,
                                                    int rowbase, int a, int tid) {
#pragma unroll
  for (int k = 0; k < 16; ++k) {
    int j = tid + k * 256;
    int r = j >> 6;
    int c4 = (j & 63) << 2;
    const float* sp = src + ((((rowbase + r) << 3) + a) << 8) + c4;
    float4 v = *(const float4*)sp;
    us4 hi = { f2bf(v.x), f2bf(v.y), f2bf(v.z), f2bf(v.w) };
    int idx = ((r << 8) + c4) ^ ((r & 7) << 3);
    *(us4*)(p + idx) = hi;
  }
}

// ---- 64x64 tile GEMM over K=256 (fc1 only): acc[4][4] += A_lds @ Wt^T ------
static __device__ __forceinline__ void mma64(const unsigned short* lds,
                                             const unsigned short* __restrict__ wt,
                                             int n0, int l16, int l4,
                                             f32x4 (&acc)[4][4]) {
#pragma unroll
  for (int ks = 0; ks < 8; ++ks) {
    s8 af[4], bw[4];
#pragma unroll
    for (int mt = 0; mt < 4; ++mt) {
      int row = mt * 16 + l16;
      int idx = ((row << 8) + ks * 32 + 8 * l4) ^ ((row & 7) << 3);
      af[mt] = *(const s8*)(lds + idx);
    }
#pragma unroll
    for (int nt = 0; nt < 4; ++nt) {
      bw[nt] = *(const s8*)(wt + ((n0 + nt * 16 + l16) << 8) + ks * 32 + 8 * l4);
    }
#pragma unroll
    for (int mt = 0; mt < 4; ++mt)
#pragma unroll
      for (int nt = 0; nt < 4; ++nt)
        acc[mt][nt] = __builtin_amdgcn_mfma_f32_16x16x32_bf16(
            af[mt], bw[nt], acc[mt][nt], 0, 0, 0);
  }
}

// ---- 64x16 subtile GEMM over K=256: acc[4] += A_lds @ wt[wrow]^T -----------
static __device__ __forceinline__ void mma16(const unsigned short* lds,
                                             const unsigned short* __restrict__ wt,
                                             int wrow, int l16, int l4,
                                             f32x4 (&acc)[4]) {
#pragma unroll
  for (int ks = 0; ks < 8; ++ks) {
    s8 bw = *(const s8*)(wt + (wrow << 8) + ks * 32 + 8 * l4);
#pragma unroll
    for (int mt = 0; mt < 4; ++mt) {
      int row = mt * 16 + l16;
      int idx = ((row << 8) + ks * 32 + 8 * l4) ^ ((row & 7) << 3);
      s8 af = *(const s8*)(lds + idx);
      acc[mt] = __builtin_amdgcn_mfma_f32_16x16x32_bf16(af, bw, acc[mt], 0, 0, 0);
    }
  }
}

// ---------------------------- fused main kernel -----------------------------
__global__ __launch_bounds__(256, 2) void fused_agent_rnn(
    const float* __restrict__ inp,  const float* __restrict__ hin,
    const float* __restrict__ b1,   const float* __restrict__ bih,
    const float* __restrict__ bhh,  const float* __restrict__ b2,
    const unsigned short* __restrict__ ws, float* __restrict__ out) {
  __shared__ __align__(16) unsigned short P0[64 * 256];  // inp_hi -> x -> h
  __shared__ __align__(16) unsigned short P1[64 * 256];  // inp_lo -> h_in
  __shared__ float RSXP[4][64], RSHP[4][64];
  __shared__ float RSX[64], RSH[64];                     // rowsum(x), rowsum(h_in)

  const unsigned short* W1H = ws + W1H_OFF;
  const unsigned short* W1L = ws + W1L_OFF;
  const unsigned short* Wih = ws + WIH_OFF;
  const unsigned short* Whh = ws + WHH_OFF;
  const unsigned short* W2t = ws + W2T_OFF;

  const int tid = threadIdx.x;
  const int a = blockIdx.x & 7;          // agent == XCD (round-robin dispatch)
  const int bt = blockIdx.x >> 3;
  const int rowbase = bt * 64;
  const int lane = tid & 63, w = tid >> 6;
  const int l16 = lane & 15, l4 = lane >> 4;
  const int n0 = w * 64;                 // wave's 64-col slice

  // ---- stage inp split; fc1: x = relu(inp @ W1 + b1), 3 split passes ----
  stage_split(P0, P1, inp, rowbase, a, tid);
  __syncthreads();

  {
    f32x4 XA[4][4];
#pragma unroll
    for (int mt = 0; mt < 4; ++mt)
#pragma unroll
      for (int nt = 0; nt < 4; ++nt) XA[mt][nt] = (f32x4){0.f, 0.f, 0.f, 0.f};
    mma64(P0, W1H + a * 65536, n0, l16, l4, XA);   // inp_hi @ W1_hi
    mma64(P1, W1H + a * 65536, n0, l16, l4, XA);   // inp_lo @ W1_hi
    mma64(P0, W1L + a * 65536, n0, l16, l4, XA);   // inp_hi @ W1_lo
    __syncthreads();                                // all fc1 reads done

    // write x (bf16) into P0; stage h_in (bf16) into P1
#pragma unroll
    for (int nt = 0; nt < 4; ++nt) {
      int col = n0 + nt * 16 + l16;
      float bb = b1[a * 256 + col];
#pragma unroll
      for (int mt = 0; mt < 4; ++mt)
#pragma unroll
        for (int r = 0; r < 4; ++r) {
          float v = fmaxf(XA[mt][nt][r] + bb, 0.f);
          int row = mt * 16 + l4 * 4 + r;
          P0[((row << 8) + col) ^ ((row & 7) << 3)] = f2bf(v);
        }
    }
  }
  stage_single(P1, hin, rowbase, a, tid);
  __syncthreads();

  // ---- exact f32 rowsums of the bf16 tiles (for centered-W correction) ----
  {
    int row = tid >> 2, qd = tid & 3;
    float sx = 0.f, sh = 0.f;
#pragma unroll 8
    for (int i = 0; i < 64; ++i) {
      int c = qd * 64 + i;
      int idx = ((row << 8) + c) ^ ((row & 7) << 3);
      sx += bf2f(P0[idx]);
      sh += bf2f(P1[idx]);
    }
    RSXP[qd][row] = sx; RSHP[qd][row] = sh;
  }
  __syncthreads();
  if (tid < 64) {
    RSX[tid] = RSXP[0][tid] + RSXP[1][tid] + RSXP[2][tid] + RSXP[3][tid];
    RSH[tid] = RSHP[0][tid] + RSHP[1][tid] + RSHP[2][tid] + RSHP[3][tid];
  }
  __syncthreads();

  const unsigned short* WihA = Wih + a * 768 * 256;
  const unsigned short* WhhA = Whh + a * 768 * 256;

  // ---- gates per 16-col subtile: only R4/T4/G4 (48 f32) live per iter ----
  f32x4 Hreg[4][4];                       // h result, persists to fc2 staging
#pragma unroll
  for (int nt = 0; nt < 4; ++nt) {
    const int col = n0 + nt * 16 + l16;   // output col == weight row (gate-local)
    f32x4 R4[4], T4[4], G4[4];

    // resetgate r = sigmoid(x@Wr + h@Wr' + 0.5*(rsx+rsh) + biases)
#pragma unroll
    for (int mt = 0; mt < 4; ++mt) R4[mt] = (f32x4){0.f, 0.f, 0.f, 0.f};
    mma16(P0, WihA, col, l16, l4, R4);
    mma16(P1, WhhA, col, l16, l4, R4);
    {
      float bb = bih[a * 768 + col] + bhh[a * 768 + col];
#pragma unroll
      for (int mt = 0; mt < 4; ++mt)
#pragma unroll
        for (int r = 0; r < 4; ++r) {
          int row = mt * 16 + l4 * 4 + r;
          R4[mt][r] = sigm(R4[mt][r] + 0.5f * (RSX[row] + RSH[row]) + bb);
        }
    }

    // t = r * (h@Wn' + 0.5*rsh + bhh_n)
#pragma unroll
    for (int mt = 0; mt < 4; ++mt) T4[mt] = (f32x4){0.f, 0.f, 0.f, 0.f};
    mma16(P1, WhhA + 512 * 256, col, l16, l4, T4);
    {
      float bb = bhh[a * 768 + 512 + col];
#pragma unroll
      for (int mt = 0; mt < 4; ++mt)
#pragma unroll
        for (int r = 0; r < 4; ++r) {
          int row = mt * 16 + l4 * 4 + r;
          T4[mt][r] = R4[mt][r] * (T4[mt][r] + 0.5f * RSH[row] + bb);
        }
    }

    // newgate = tanh(x@Wn + 0.5*rsx + bih_n + t)
#pragma unroll
    for (int mt = 0; mt < 4; ++mt) G4[mt] = (f32x4){0.f, 0.f, 0.f, 0.f};
    mma16(P0, WihA + 512 * 256, col, l16, l4, G4);
    {
      float bb = bih[a * 768 + 512 + col];
#pragma unroll
      for (int mt = 0; mt < 4; ++mt)
#pragma unroll
        for (int r = 0; r < 4; ++r) {
          int row = mt * 16 + l4 * 4 + r;
          G4[mt][r] = tanh_(G4[mt][r] + 0.5f * RSX[row] + bb + T4[mt][r]);
        }
    }

    // inputgate (reuse R4), combine, write h
#pragma unroll
    for (int mt = 0; mt < 4; ++mt) R4[mt] = (f32x4){0.f, 0.f, 0.f, 0.f};
    mma16(P0, WihA + 256 * 256, col, l16, l4, R4);
    mma16(P1, WhhA + 256 * 256, col, l16, l4, R4);
    {
      float bb = bih[a * 768 + 256 + col] + bhh[a * 768 + 256 + col];
#pragma unroll
      for (int mt = 0; mt < 4; ++mt)
#pragma unroll
        for (int r = 0; r < 4; ++r) {
          int row = mt * 16 + l4 * 4 + r;
          float ig = sigm(R4[mt][r] + 0.5f * (RSX[row] + RSH[row]) + bb);
          float hv = bf2f(P1[((row << 8) + col) ^ ((row & 7) << 3)]);
          float ng = G4[mt][r];
          float h = ng + ig * (hv - ng);
          out[QSIZE + ((((rowbase + row) << 3) + a) << 8) + col] = h;
          Hreg[nt][mt][r] = h;
        }
    }
  }
  __syncthreads();                        // all gate reads of P0/P1 done

  // stash h (bf16) into P0 for fc2
#pragma unroll
  for (int nt = 0; nt < 4; ++nt) {
    int col = n0 + nt * 16 + l16;
#pragma unroll
    for (int mt = 0; mt < 4; ++mt)
#pragma unroll
      for (int r = 0; r < 4; ++r) {
        int row = mt * 16 + l4 * 4 + r;
        P0[((row << 8) + col) ^ ((row & 7) << 3)] = f2bf(Hreg[nt][mt][r]);
      }
  }
  __syncthreads();

  // ---- q = relu(h @ W2 + b2), N padded to 32, wave w -> 16 rows ----
  f32x4 qa[2];
  qa[0] = (f32x4){0.f, 0.f, 0.f, 0.f};
  qa[1] = (f32x4){0.f, 0.f, 0.f, 0.f};
#pragma unroll
  for (int ks = 0; ks < 8; ++ks) {
    int row = w * 16 + l16;
    int idx = ((row << 8) + ks * 32 + 8 * l4) ^ ((row & 7) << 3);
    s8 af = *(const s8*)(P0 + idx);
#pragma unroll
    for (int nt = 0; nt < 2; ++nt) {
      s8 bw = *(const s8*)(W2t + ((a * 32 + nt * 16 + l16) << 8) + ks * 32 + 8 * l4);
      qa[nt] = __builtin_amdgcn_mfma_f32_16x16x32_bf16(af, bw, qa[nt], 0, 0, 0);
    }
  }
#pragma unroll
  for (int nt = 0; nt < 2; ++nt) {
    int col = nt * 16 + l16;
    if (col < 30) {
      float bb = b2[a * 30 + col];
#pragma unroll
      for (int r = 0; r < 4; ++r) {
        int row = w * 16 + l4 * 4 + r;
        out[(((rowbase + row) << 3) + a) * 30 + col] = fmaxf(qa[nt][r] + bb, 0.f);
      }
    }
  }
}

extern "C" void kernel_launch(void* const* d_in, const int* in_sizes, int n_in,
                              void* d_out, int out_size, void* d_ws, size_t ws_size,
                              hipStream_t stream) {
  const float* inputs = (const float*)d_in[0];
  const float* hidden = (const float*)d_in[1];
  const float* fc1w   = (const float*)d_in[2];
  const float* fc1b   = (const float*)d_in[3];
  const float* rihw   = (const float*)d_in[4];
  const float* rihb   = (const float*)d_in[5];
  const float* rhhw   = (const float*)d_in[6];
  const float* rhhb   = (const float*)d_in[7];
  const float* fc2w   = (const float*)d_in[8];
  const float* fc2b   = (const float*)d_in[9];
  unsigned short* ws  = (unsigned short*)d_ws;
  float* out          = (float*)d_out;

  hipLaunchKernelGGL(prep_weights, dim3(3648), dim3(256), 0, stream,
                     fc1w, rihw, rhhw, fc2w, ws);
  hipLaunchKernelGGL(fused_agent_rnn, dim3(512), dim3(256), 0, stream,
                     inputs, hidden, fc1b, rihb, rhhb, fc2b, ws, out);
}

// Round 4
// 205.250 us; speedup vs baseline: 2.0496x; 2.0496x over previous
//
#include <hip/hip_runtime.h>

// ---------------------------------------------------------------------------
// LatentMixtureAllRNNAgent: fused per-agent fc1 -> GRU cell -> fc2 on MI355X.
// Round 4: kill VGPR spill (rounds 2/3: VGPR_Count pinned at 128, ~400 MB
// scratch writes + up to 250 MB fills).
//   (a) __launch_bounds__(256, 1): lift the 128-reg cap (LDS already limits
//       occupancy to 2 blocks/CU, so no occupancy cost).
//   (b) no persistent Hreg: gates write h(f32) to out, then re-stage h from
//       global for fc2 (extra 33.5 MB read ~5us << spill traffic).
// Numerics unchanged from round 2/3 (split-bf16 fc1, centered gate weights +
// exact f32 rowsum corrections, bf16 fc2): absmax was 1.0, keep it.
// ---------------------------------------------------------------------------

typedef __attribute__((ext_vector_type(4))) float f32x4;
typedef __attribute__((ext_vector_type(8))) short s8;     // 8 bf16 (4 VGPRs)
typedef __attribute__((ext_vector_type(4))) unsigned short us4;

#define QSIZE   983040      /* 32768*30 */
#define W1H_OFF 0
#define W1L_OFF 524288
#define WIH_OFF 1048576
#define WHH_OFF 2621440
#define W2T_OFF 4194304

static __device__ __forceinline__ unsigned short f2bf(float f) {
  union { float f; unsigned u; } v; v.f = f;
  unsigned r = v.u + 0x7FFFu + ((v.u >> 16) & 1u);   // RNE
  return (unsigned short)(r >> 16);
}
static __device__ __forceinline__ float bf2f(unsigned short u) {
  union { unsigned u; float f; } v; v.u = ((unsigned)u) << 16;
  return v.f;
}
static __device__ __forceinline__ float sigm(float x) {
  return 1.0f / (1.0f + __expf(-x));
}
static __device__ __forceinline__ float tanh_(float x) {
  return 1.0f - 2.0f / (__expf(2.0f * x) + 1.0f);    // saturates correctly
}

// ------------- prep: f32 [a][k][n] -> bf16 [a][n][k] planes in ws -----------
__global__ void prep_weights(const float* __restrict__ fc1w,
                             const float* __restrict__ rihw,
                             const float* __restrict__ rhhw,
                             const float* __restrict__ fc2w,
                             unsigned short* __restrict__ ws) {
  int q = blockIdx.x * 256 + threadIdx.x;   // one us4 (4 k-values) per thread
  if (q < 131072) {                         // fc1: hi + lo planes
    int a = q >> 14, rem = q & 16383, k4 = rem >> 8, n = rem & 255;
    const float* s = fc1w + a * 65536 + (k4 * 4) * 256 + n;
    float v0 = s[0], v1 = s[256], v2 = s[512], v3 = s[768];
    us4 hi = { f2bf(v0), f2bf(v1), f2bf(v2), f2bf(v3) };
    us4 lo = { f2bf(v0 - bf2f(hi[0])), f2bf(v1 - bf2f(hi[1])),
               f2bf(v2 - bf2f(hi[2])), f2bf(v3 - bf2f(hi[3])) };
    int o = ((a * 256 + n) << 8) + k4 * 4;
    *(us4*)(ws + W1H_OFF + o) = hi;
    *(us4*)(ws + W1L_OFF + o) = lo;
  } else if (q < 524288) {                  // rnn_ih, centered (w - 0.5)
    int t = q - 131072;
    int a = t / 49152, rem = t % 49152, k4 = rem / 768, n = rem % 768;
    const float* s = rihw + a * 196608 + (k4 * 4) * 768 + n;
    us4 v = { f2bf(s[0] - 0.5f), f2bf(s[768] - 0.5f),
              f2bf(s[1536] - 0.5f), f2bf(s[2304] - 0.5f) };
    *(us4*)(ws + WIH_OFF + ((a * 768 + n) << 8) + k4 * 4) = v;
  } else if (q < 917504) {                  // rnn_hh, centered
    int t = q - 524288;
    int a = t / 49152, rem = t % 49152, k4 = rem / 768, n = rem % 768;
    const float* s = rhhw + a * 196608 + (k4 * 4) * 768 + n;
    us4 v = { f2bf(s[0] - 0.5f), f2bf(s[768] - 0.5f),
              f2bf(s[1536] - 0.5f), f2bf(s[2304] - 0.5f) };
    *(us4*)(ws + WHH_OFF + ((a * 768 + n) << 8) + k4 * 4) = v;
  } else if (q < 933888) {                  // fc2: plain, pad 30->32
    int t = q - 917504;
    int a = t >> 11, rem = t & 2047, k4 = rem >> 5, n = rem & 31;
    us4 v = { 0, 0, 0, 0 };
    if (n < 30) {
      const float* s = fc2w + a * 7680 + (k4 * 4) * 30 + n;
      v = (us4){ f2bf(s[0]), f2bf(s[30]), f2bf(s[60]), f2bf(s[90]) };
    }
    *(us4*)(ws + W2T_OFF + ((a * 32 + n) << 8) + k4 * 4) = v;
  }
}

// ------- stage 64x256 f32 tile -> split bf16 (hi plane p0, lo plane p1) -----
static __device__ __forceinline__ void stage_split(unsigned short* p0,
                                                   unsigned short* p1,
                                                   const float* __restrict__ src,
                                                   int rowbase, int a, int tid) {
#pragma unroll
  for (int k = 0; k < 16; ++k) {
    int j = tid + k * 256;
    int r = j >> 6;
    int c4 = (j & 63) << 2;
    const float* p = src + ((((rowbase + r) << 3) + a) << 8) + c4;
    float4 v = *(const float4*)p;
    us4 hi = { f2bf(v.x), f2bf(v.y), f2bf(v.z), f2bf(v.w) };
    us4 lo = { f2bf(v.x - bf2f(hi[0])), f2bf(v.y - bf2f(hi[1])),
               f2bf(v.z - bf2f(hi[2])), f2bf(v.w - bf2f(hi[3])) };
    int idx = ((r << 8) + c4) ^ ((r & 7) << 3);   // XOR swizzle (16B blocks)
    *(us4*)(p0 + idx) = hi;
    *(us4*)(p1 + idx) = lo;
  }
}

// ------------- stage 64x256 f32 tile -> single bf16 plane -------------------
static __device__ __forceinline__ void stage_single(unsigned short* p,
                                                    const float* __restrict__ src,
                                                    int rowbase, int a, int tid) {
#pragma unroll
  for (int k = 0; k < 16; ++k) {
    int j = tid + k * 256;
    int r = j >> 6;
    int c4 = (j & 63) << 2;
    const float* sp = src + ((((rowbase + r) << 3) + a) << 8) + c4;
    float4 v = *(const float4*)sp;
    us4 hi = { f2bf(v.x), f2bf(v.y), f2bf(v.z), f2bf(v.w) };
    int idx = ((r << 8) + c4) ^ ((r & 7) << 3);
    *(us4*)(p + idx) = hi;
  }
}

// ---- 64x64 tile GEMM over K=256 (fc1 only): acc[4][4] += A_lds @ Wt^T ------
static __device__ __forceinline__ void mma64(const unsigned short* lds,
                                             const unsigned short* __restrict__ wt,
                                             int n0, int l16, int l4,
                                             f32x4 (&acc)[4][4]) {
#pragma unroll
  for (int ks = 0; ks < 8; ++ks) {
    s8 af[4], bw[4];
#pragma unroll
    for (int mt = 0; mt < 4; ++mt) {
      int row = mt * 16 + l16;
      int idx = ((row << 8) + ks * 32 + 8 * l4) ^ ((row & 7) << 3);
      af[mt] = *(const s8*)(lds + idx);
    }
#pragma unroll
    for (int nt = 0; nt < 4; ++nt) {
      bw[nt] = *(const s8*)(wt + ((n0 + nt * 16 + l16) << 8) + ks * 32 + 8 * l4);
    }
#pragma unroll
    for (int mt = 0; mt < 4; ++mt)
#pragma unroll
      for (int nt = 0; nt < 4; ++nt)
        acc[mt][nt] = __builtin_amdgcn_mfma_f32_16x16x32_bf16(
            af[mt], bw[nt], acc[mt][nt], 0, 0, 0);
  }
}

// ---- 64x16 subtile GEMM over K=256: acc[4] += A_lds @ wt[wrow]^T -----------
static __device__ __forceinline__ void mma16(const unsigned short* lds,
                                             const unsigned short* __restrict__ wt,
                                             int wrow, int l16, int l4,
                                             f32x4 (&acc)[4]) {
#pragma unroll
  for (int ks = 0; ks < 8; ++ks) {
    s8 bw = *(const s8*)(wt + (wrow << 8) + ks * 32 + 8 * l4);
#pragma unroll
    for (int mt = 0; mt < 4; ++mt) {
      int row = mt * 16 + l16;
      int idx = ((row << 8) + ks * 32 + 8 * l4) ^ ((row & 7) << 3);
      s8 af = *(const s8*)(lds + idx);
      acc[mt] = __builtin_amdgcn_mfma_f32_16x16x32_bf16(af, bw, acc[mt], 0, 0, 0);
    }
  }
}

// ---------------------------- fused main kernel -----------------------------
__global__ __launch_bounds__(256, 1) void fused_agent_rnn(
    const float* __restrict__ inp,  const float* __restrict__ hin,
    const float* __restrict__ b1,   const float* __restrict__ bih,
    const float* __restrict__ bhh,  const float* __restrict__ b2,
    const unsigned short* __restrict__ ws, float* __restrict__ out) {
  __shared__ __align__(16) unsigned short P0[64 * 256];  // inp_hi -> x -> h
  __shared__ __align__(16) unsigned short P1[64 * 256];  // inp_lo -> h_in
  __shared__ float RSXP[4][64], RSHP[4][64];
  __shared__ float RSX[64], RSH[64];                     // rowsum(x), rowsum(h_in)

  const unsigned short* W1H = ws + W1H_OFF;
  const unsigned short* W1L = ws + W1L_OFF;
  const unsigned short* Wih = ws + WIH_OFF;
  const unsigned short* Whh = ws + WHH_OFF;
  const unsigned short* W2t = ws + W2T_OFF;

  const int tid = threadIdx.x;
  const int a = blockIdx.x & 7;          // agent == XCD (round-robin dispatch)
  const int bt = blockIdx.x >> 3;
  const int rowbase = bt * 64;
  const int lane = tid & 63, w = tid >> 6;
  const int l16 = lane & 15, l4 = lane >> 4;
  const int n0 = w * 64;                 // wave's 64-col slice

  // ---- stage inp split; fc1: x = relu(inp @ W1 + b1), 3 split passes ----
  stage_split(P0, P1, inp, rowbase, a, tid);
  __syncthreads();

  {
    f32x4 XA[4][4];
#pragma unroll
    for (int mt = 0; mt < 4; ++mt)
#pragma unroll
      for (int nt = 0; nt < 4; ++nt) XA[mt][nt] = (f32x4){0.f, 0.f, 0.f, 0.f};
    mma64(P0, W1H + a * 65536, n0, l16, l4, XA);   // inp_hi @ W1_hi
    mma64(P1, W1H + a * 65536, n0, l16, l4, XA);   // inp_lo @ W1_hi
    mma64(P0, W1L + a * 65536, n0, l16, l4, XA);   // inp_hi @ W1_lo
    __syncthreads();                                // all fc1 reads done

    // write x (bf16) into P0; stage h_in (bf16) into P1
#pragma unroll
    for (int nt = 0; nt < 4; ++nt) {
      int col = n0 + nt * 16 + l16;
      float bb = b1[a * 256 + col];
#pragma unroll
      for (int mt = 0; mt < 4; ++mt)
#pragma unroll
        for (int r = 0; r < 4; ++r) {
          float v = fmaxf(XA[mt][nt][r] + bb, 0.f);
          int row = mt * 16 + l4 * 4 + r;
          P0[((row << 8) + col) ^ ((row & 7) << 3)] = f2bf(v);
        }
    }
  }
  stage_single(P1, hin, rowbase, a, tid);
  __syncthreads();

  // ---- exact f32 rowsums of the bf16 tiles (for centered-W correction) ----
  {
    int row = tid >> 2, qd = tid & 3;
    float sx = 0.f, sh = 0.f;
#pragma unroll
    for (int i = 0; i < 16; ++i) {
      int c = qd * 64 + i * 4;
      int idx = ((row << 8) + c) ^ ((row & 7) << 3);   // 4-col groups stay contiguous
      us4 vx = *(const us4*)(P0 + idx);
      us4 vh = *(const us4*)(P1 + idx);
      sx += bf2f(vx[0]) + bf2f(vx[1]) + bf2f(vx[2]) + bf2f(vx[3]);
      sh += bf2f(vh[0]) + bf2f(vh[1]) + bf2f(vh[2]) + bf2f(vh[3]);
    }
    RSXP[qd][row] = sx; RSHP[qd][row] = sh;
  }
  __syncthreads();
  if (tid < 64) {
    RSX[tid] = RSXP[0][tid] + RSXP[1][tid] + RSXP[2][tid] + RSXP[3][tid];
    RSH[tid] = RSHP[0][tid] + RSHP[1][tid] + RSHP[2][tid] + RSHP[3][tid];
  }
  __syncthreads();

  const unsigned short* WihA = Wih + a * 768 * 256;
  const unsigned short* WhhA = Whh + a * 768 * 256;

  // ---- gates per 16-col subtile: only R4/T4/G4 (48 f32) live per iter;
  //      h goes straight to global (re-staged later for fc2) ----
#pragma unroll
  for (int nt = 0; nt < 4; ++nt) {
    const int col = n0 + nt * 16 + l16;   // output col == weight row (gate-local)
    f32x4 R4[4], T4[4], G4[4];

    // resetgate r = sigmoid(x@Wr + h@Wr' + 0.5*(rsx+rsh) + biases)
#pragma unroll
    for (int mt = 0; mt < 4; ++mt) R4[mt] = (f32x4){0.f, 0.f, 0.f, 0.f};
    mma16(P0, WihA, col, l16, l4, R4);
    mma16(P1, WhhA, col, l16, l4, R4);
    {
      float bb = bih[a * 768 + col] + bhh[a * 768 + col];
#pragma unroll
      for (int mt = 0; mt < 4; ++mt)
#pragma unroll
        for (int r = 0; r < 4; ++r) {
          int row = mt * 16 + l4 * 4 + r;
          R4[mt][r] = sigm(R4[mt][r] + 0.5f * (RSX[row] + RSH[row]) + bb);
        }
    }

    // t = r * (h@Wn' + 0.5*rsh + bhh_n)
#pragma unroll
    for (int mt = 0; mt < 4; ++mt) T4[mt] = (f32x4){0.f, 0.f, 0.f, 0.f};
    mma16(P1, WhhA + 512 * 256, col, l16, l4, T4);
    {
      float bb = bhh[a * 768 + 512 + col];
#pragma unroll
      for (int mt = 0; mt < 4; ++mt)
#pragma unroll
        for (int r = 0; r < 4; ++r) {
          int row = mt * 16 + l4 * 4 + r;
          T4[mt][r] = R4[mt][r] * (T4[mt][r] + 0.5f * RSH[row] + bb);
        }
    }

    // newgate = tanh(x@Wn + 0.5*rsx + bih_n + t)  (G4 = ng)
#pragma unroll
    for (int mt = 0; mt < 4; ++mt) G4[mt] = (f32x4){0.f, 0.f, 0.f, 0.f};
    mma16(P0, WihA + 512 * 256, col, l16, l4, G4);
    {
      float bb = bih[a * 768 + 512 + col];
#pragma unroll
      for (int mt = 0; mt < 4; ++mt)
#pragma unroll
        for (int r = 0; r < 4; ++r) {
          int row = mt * 16 + l4 * 4 + r;
          G4[mt][r] = tanh_(G4[mt][r] + 0.5f * RSX[row] + bb + T4[mt][r]);
        }
    }

    // inputgate (reuse R4), combine, write h to global only
#pragma unroll
    for (int mt = 0; mt < 4; ++mt) R4[mt] = (f32x4){0.f, 0.f, 0.f, 0.f};
    mma16(P0, WihA + 256 * 256, col, l16, l4, R4);
    mma16(P1, WhhA + 256 * 256, col, l16, l4, R4);
    {
      float bb = bih[a * 768 + 256 + col] + bhh[a * 768 + 256 + col];
#pragma unroll
      for (int mt = 0; mt < 4; ++mt)
#pragma unroll
        for (int r = 0; r < 4; ++r) {
          int row = mt * 16 + l4 * 4 + r;
          float ig = sigm(R4[mt][r] + 0.5f * (RSX[row] + RSH[row]) + bb);
          float hv = bf2f(P1[((row << 8) + col) ^ ((row & 7) << 3)]);
          float ng = G4[mt][r];
          out[QSIZE + ((((rowbase + row) << 3) + a) << 8) + col]
              = ng + ig * (hv - ng);
        }
    }
  }
  __syncthreads();   // gates done reading P0/P1; h stores drained (vmcnt(0))

  // re-stage h (f32 in out+QSIZE) -> bf16 P0 for fc2
  stage_single(P0, out + QSIZE, rowbase, a, tid);
  __syncthreads();

  // ---- q = relu(h @ W2 + b2), N padded to 32, wave w -> 16 rows ----
  f32x4 qa[2];
  qa[0] = (f32x4){0.f, 0.f, 0.f, 0.f};
  qa[1] = (f32x4){0.f, 0.f, 0.f, 0.f};
#pragma unroll
  for (int ks = 0; ks < 8; ++ks) {
    int row = w * 16 + l16;
    int idx = ((row << 8) + ks * 32 + 8 * l4) ^ ((row & 7) << 3);
    s8 af = *(const s8*)(P0 + idx);
#pragma unroll
    for (int nt = 0; nt < 2; ++nt) {
      s8 bw = *(const s8*)(W2t + ((a * 32 + nt * 16 + l16) << 8) + ks * 32 + 8 * l4);
      qa[nt] = __builtin_amdgcn_mfma_f32_16x16x32_bf16(af, bw, qa[nt], 0, 0, 0);
    }
  }
#pragma unroll
  for (int nt = 0; nt < 2; ++nt) {
    int col = nt * 16 + l16;
    if (col < 30) {
      float bb = b2[a * 30 + col];
#pragma unroll
      for (int r = 0; r < 4; ++r) {
        int row = w * 16 + l4 * 4 + r;
        out[(((rowbase + row) << 3) + a) * 30 + col] = fmaxf(qa[nt][r] + bb, 0.f);
      }
    }
  }
}

extern "C" void kernel_launch(void* const* d_in, const int* in_sizes, int n_in,
                              void* d_out, int out_size, void* d_ws, size_t ws_size,
                              hipStream_t stream) {
  const float* inputs = (const float*)d_in[0];
  const float* hidden = (const float*)d_in[1];
  const float* fc1w   = (const float*)d_in[2];
  const float* fc1b   = (const float*)d_in[3];
  const float* rihw   = (const float*)d_in[4];
  const float* rihb   = (const float*)d_in[5];
  const float* rhhw   = (const float*)d_in[6];
  const float* rhhb   = (const float*)d_in[7];
  const float* fc2w   = (const float*)d_in[8];
  const float* fc2b   = (const float*)d_in[9];
  unsigned short* ws  = (unsigned short*)d_ws;
  float* out          = (float*)d_out;

  hipLaunchKernelGGL(prep_weights, dim3(3648), dim3(256), 0, stream,
                     fc1w, rihw, rhhw, fc2w, ws);
  hipLaunchKernelGGL(fused_agent_rnn, dim3(512), dim3(256), 0, stream,
                     inputs, hidden, fc1b, rihb, rhhb, fc2b, ws, out);
}

// Round 5
// 185.931 us; speedup vs baseline: 2.2626x; 1.1039x over previous
//
#include <hip/hip_runtime.h>

// ---------------------------------------------------------------------------
// LatentMixtureAllRNNAgent: fused per-agent fc1 -> GRU cell -> fc2 on MI355X.
// Round 5: occupancy fix. Round 4 eliminated spills (VGPR=256) but landed at
// 1 block/CU (Occ 11.9%) -> latency-bound, all pipes <10%. This round:
//   - 32-row tiles (grid 1024 = 128 tiles x 8 agents), LDS ~34 KB -> 4 blk/CU
//   - accumulators halved ([2] not [4]) -> fits the empirical 128-VGPR cap of
//     __launch_bounds__(256,2) with no spill (round-3 failure had Hreg + [4])
//   - 16 waves/CU across 4 phase-independent blocks hides L2 weight latency
// Numerics IDENTICAL to rounds 2-4 (absmax 1.0): split-bf16 fc1, centered
// gate weights + exact f32 rowsum correction, bf16 fc2.
// Empirical toolchain note: launch_bounds(256,1)->256 VGPRs, (256,2)->128.
// ---------------------------------------------------------------------------

typedef __attribute__((ext_vector_type(4))) float f32x4;
typedef __attribute__((ext_vector_type(8))) short s8;     // 8 bf16 (4 VGPRs)
typedef __attribute__((ext_vector_type(4))) unsigned short us4;

#define QSIZE   983040      /* 32768*30 */
#define W1H_OFF 0
#define W1L_OFF 524288
#define WIH_OFF 1048576
#define WHH_OFF 2621440
#define W2T_OFF 4194304

static __device__ __forceinline__ unsigned short f2bf(float f) {
  union { float f; unsigned u; } v; v.f = f;
  unsigned r = v.u + 0x7FFFu + ((v.u >> 16) & 1u);   // RNE
  return (unsigned short)(r >> 16);
}
static __device__ __forceinline__ float bf2f(unsigned short u) {
  union { unsigned u; float f; } v; v.u = ((unsigned)u) << 16;
  return v.f;
}
static __device__ __forceinline__ float sigm(float x) {
  return 1.0f / (1.0f + __expf(-x));
}
static __device__ __forceinline__ float tanh_(float x) {
  return 1.0f - 2.0f / (__expf(2.0f * x) + 1.0f);    // saturates correctly
}

// ------------- prep: f32 [a][k][n] -> bf16 [a][n][k] planes in ws -----------
__global__ void prep_weights(const float* __restrict__ fc1w,
                             const float* __restrict__ rihw,
                             const float* __restrict__ rhhw,
                             const float* __restrict__ fc2w,
                             unsigned short* __restrict__ ws) {
  int q = blockIdx.x * 256 + threadIdx.x;   // one us4 (4 k-values) per thread
  if (q < 131072) {                         // fc1: hi + lo planes
    int a = q >> 14, rem = q & 16383, k4 = rem >> 8, n = rem & 255;
    const float* s = fc1w + a * 65536 + (k4 * 4) * 256 + n;
    float v0 = s[0], v1 = s[256], v2 = s[512], v3 = s[768];
    us4 hi = { f2bf(v0), f2bf(v1), f2bf(v2), f2bf(v3) };
    us4 lo = { f2bf(v0 - bf2f(hi[0])), f2bf(v1 - bf2f(hi[1])),
               f2bf(v2 - bf2f(hi[2])), f2bf(v3 - bf2f(hi[3])) };
    int o = ((a * 256 + n) << 8) + k4 * 4;
    *(us4*)(ws + W1H_OFF + o) = hi;
    *(us4*)(ws + W1L_OFF + o) = lo;
  } else if (q < 524288) {                  // rnn_ih, centered (w - 0.5)
    int t = q - 131072;
    int a = t / 49152, rem = t % 49152, k4 = rem / 768, n = rem % 768;
    const float* s = rihw + a * 196608 + (k4 * 4) * 768 + n;
    us4 v = { f2bf(s[0] - 0.5f), f2bf(s[768] - 0.5f),
              f2bf(s[1536] - 0.5f), f2bf(s[2304] - 0.5f) };
    *(us4*)(ws + WIH_OFF + ((a * 768 + n) << 8) + k4 * 4) = v;
  } else if (q < 917504) {                  // rnn_hh, centered
    int t = q - 524288;
    int a = t / 49152, rem = t % 49152, k4 = rem / 768, n = rem % 768;
    const float* s = rhhw + a * 196608 + (k4 * 4) * 768 + n;
    us4 v = { f2bf(s[0] - 0.5f), f2bf(s[768] - 0.5f),
              f2bf(s[1536] - 0.5f), f2bf(s[2304] - 0.5f) };
    *(us4*)(ws + WHH_OFF + ((a * 768 + n) << 8) + k4 * 4) = v;
  } else if (q < 933888) {                  // fc2: plain, pad 30->32
    int t = q - 917504;
    int a = t >> 11, rem = t & 2047, k4 = rem >> 5, n = rem & 31;
    us4 v = { 0, 0, 0, 0 };
    if (n < 30) {
      const float* s = fc2w + a * 7680 + (k4 * 4) * 30 + n;
      v = (us4){ f2bf(s[0]), f2bf(s[30]), f2bf(s[60]), f2bf(s[90]) };
    }
    *(us4*)(ws + W2T_OFF + ((a * 32 + n) << 8) + k4 * 4) = v;
  }
}

// ------- stage 32x256 f32 tile -> split bf16 (hi plane p0, lo plane p1) -----
static __device__ __forceinline__ void stage_split(unsigned short* p0,
                                                   unsigned short* p1,
                                                   const float* __restrict__ src,
                                                   int rowbase, int a, int tid) {
#pragma unroll
  for (int k = 0; k < 8; ++k) {
    int j = tid + k * 256;                  // 0..2047 float4s
    int r = j >> 6;                         // tile row 0..31
    int c4 = (j & 63) << 2;
    const float* p = src + ((((rowbase + r) << 3) + a) << 8) + c4;
    float4 v = *(const float4*)p;
    us4 hi = { f2bf(v.x), f2bf(v.y), f2bf(v.z), f2bf(v.w) };
    us4 lo = { f2bf(v.x - bf2f(hi[0])), f2bf(v.y - bf2f(hi[1])),
               f2bf(v.z - bf2f(hi[2])), f2bf(v.w - bf2f(hi[3])) };
    int idx = ((r << 8) + c4) ^ ((r & 7) << 3);   // XOR swizzle (16B blocks)
    *(us4*)(p0 + idx) = hi;
    *(us4*)(p1 + idx) = lo;
  }
}

// ------------- stage 32x256 f32 tile -> single bf16 plane -------------------
static __device__ __forceinline__ void stage_single(unsigned short* p,
                                                    const float* __restrict__ src,
                                                    int rowbase, int a, int tid) {
#pragma unroll
  for (int k = 0; k < 8; ++k) {
    int j = tid + k * 256;
    int r = j >> 6;
    int c4 = (j & 63) << 2;
    const float* sp = src + ((((rowbase + r) << 3) + a) << 8) + c4;
    float4 v = *(const float4*)sp;
    us4 hi = { f2bf(v.x), f2bf(v.y), f2bf(v.z), f2bf(v.w) };
    int idx = ((r << 8) + c4) ^ ((r & 7) << 3);
    *(us4*)(p + idx) = hi;
  }
}

// ---- 32x64 tile GEMM over K=256 (fc1): acc[2][4] += A_lds @ Wt^T -----------
static __device__ __forceinline__ void mma64(const unsigned short* lds,
                                             const unsigned short* __restrict__ wt,
                                             int n0, int l16, int l4,
                                             f32x4 (&acc)[2][4]) {
#pragma unroll
  for (int ks = 0; ks < 8; ++ks) {
    s8 af[2], bw[4];
#pragma unroll
    for (int mt = 0; mt < 2; ++mt) {
      int row = mt * 16 + l16;
      int idx = ((row << 8) + ks * 32 + 8 * l4) ^ ((row & 7) << 3);
      af[mt] = *(const s8*)(lds + idx);
    }
#pragma unroll
    for (int nt = 0; nt < 4; ++nt) {
      bw[nt] = *(const s8*)(wt + ((n0 + nt * 16 + l16) << 8) + ks * 32 + 8 * l4);
    }
#pragma unroll
    for (int mt = 0; mt < 2; ++mt)
#pragma unroll
      for (int nt = 0; nt < 4; ++nt)
        acc[mt][nt] = __builtin_amdgcn_mfma_f32_16x16x32_bf16(
            af[mt], bw[nt], acc[mt][nt], 0, 0, 0);
  }
}

// ---- 32x16 subtile GEMM over K=256: acc[2] += A_lds @ wt[wrow]^T -----------
static __device__ __forceinline__ void mma16(const unsigned short* lds,
                                             const unsigned short* __restrict__ wt,
                                             int wrow, int l16, int l4,
                                             f32x4 (&acc)[2]) {
#pragma unroll
  for (int ks = 0; ks < 8; ++ks) {
    s8 bw = *(const s8*)(wt + (wrow << 8) + ks * 32 + 8 * l4);
#pragma unroll
    for (int mt = 0; mt < 2; ++mt) {
      int row = mt * 16 + l16;
      int idx = ((row << 8) + ks * 32 + 8 * l4) ^ ((row & 7) << 3);
      s8 af = *(const s8*)(lds + idx);
      acc[mt] = __builtin_amdgcn_mfma_f32_16x16x32_bf16(af, bw, acc[mt], 0, 0, 0);
    }
  }
}

// ---------------------------- fused main kernel -----------------------------
__global__ __launch_bounds__(256, 2) void fused_agent_rnn(
    const float* __restrict__ inp,  const float* __restrict__ hin,
    const float* __restrict__ b1,   const float* __restrict__ bih,
    const float* __restrict__ bhh,  const float* __restrict__ b2,
    const unsigned short* __restrict__ ws, float* __restrict__ out) {
  __shared__ __align__(16) unsigned short P0[32 * 256];  // inp_hi -> x -> h
  __shared__ __align__(16) unsigned short P1[32 * 256];  // inp_lo -> h_in
  __shared__ float RSXP[8][32], RSHP[8][32];
  __shared__ float RSX[32], RSH[32];                     // rowsum(x), rowsum(h_in)

  const unsigned short* W1H = ws + W1H_OFF;
  const unsigned short* W1L = ws + W1L_OFF;
  const unsigned short* Wih = ws + WIH_OFF;
  const unsigned short* Whh = ws + WHH_OFF;
  const unsigned short* W2t = ws + W2T_OFF;

  const int tid = threadIdx.x;
  const int a = blockIdx.x & 7;          // agent == XCD (round-robin dispatch)
  const int bt = blockIdx.x >> 3;        // 0..127
  const int rowbase = bt * 32;
  const int lane = tid & 63, w = tid >> 6;
  const int l16 = lane & 15, l4 = lane >> 4;
  const int n0 = w * 64;                 // wave's 64-col slice

  // ---- stage inp split; fc1: x = relu(inp @ W1 + b1), 3 split passes ----
  stage_split(P0, P1, inp, rowbase, a, tid);
  __syncthreads();

  {
    f32x4 XA[2][4];
#pragma unroll
    for (int mt = 0; mt < 2; ++mt)
#pragma unroll
      for (int nt = 0; nt < 4; ++nt) XA[mt][nt] = (f32x4){0.f, 0.f, 0.f, 0.f};
    mma64(P0, W1H + a * 65536, n0, l16, l4, XA);   // inp_hi @ W1_hi
    mma64(P1, W1H + a * 65536, n0, l16, l4, XA);   // inp_lo @ W1_hi
    mma64(P0, W1L + a * 65536, n0, l16, l4, XA);   // inp_hi @ W1_lo
    __syncthreads();                                // all fc1 reads done

    // write x (bf16) into P0; stage h_in (bf16) into P1
#pragma unroll
    for (int nt = 0; nt < 4; ++nt) {
      int col = n0 + nt * 16 + l16;
      float bb = b1[a * 256 + col];
#pragma unroll
      for (int mt = 0; mt < 2; ++mt)
#pragma unroll
        for (int r = 0; r < 4; ++r) {
          float v = fmaxf(XA[mt][nt][r] + bb, 0.f);
          int row = mt * 16 + l4 * 4 + r;
          P0[((row << 8) + col) ^ ((row & 7) << 3)] = f2bf(v);
        }
    }
  }
  stage_single(P1, hin, rowbase, a, tid);
  __syncthreads();

  // ---- exact f32 rowsums of the bf16 tiles (for centered-W correction) ----
  {
    int row = tid >> 3, qd = tid & 7;    // 8 partials x 32 rows
    float sx = 0.f, sh = 0.f;
#pragma unroll
    for (int i = 0; i < 8; ++i) {
      int c = qd * 32 + i * 4;
      int idx = ((row << 8) + c) ^ ((row & 7) << 3);  // 4-col groups contiguous
      us4 vx = *(const us4*)(P0 + idx);
      us4 vh = *(const us4*)(P1 + idx);
      sx += bf2f(vx[0]) + bf2f(vx[1]) + bf2f(vx[2]) + bf2f(vx[3]);
      sh += bf2f(vh[0]) + bf2f(vh[1]) + bf2f(vh[2]) + bf2f(vh[3]);
    }
    RSXP[qd][row] = sx; RSHP[qd][row] = sh;
  }
  __syncthreads();
  if (tid < 32) {
    float sx = 0.f, sh = 0.f;
#pragma unroll
    for (int qd = 0; qd < 8; ++qd) { sx += RSXP[qd][tid]; sh += RSHP[qd][tid]; }
    RSX[tid] = sx; RSH[tid] = sh;
  }
  __syncthreads();

  const unsigned short* WihA = Wih + a * 768 * 256;
  const unsigned short* WhhA = Whh + a * 768 * 256;

  // ---- gates per 16-col subtile: R/T/G [2] accs (~24 f32 live) ----
#pragma unroll
  for (int nt = 0; nt < 4; ++nt) {
    const int col = n0 + nt * 16 + l16;   // output col == weight row (gate-local)
    f32x4 R4[2], T4[2], G4[2];

    // resetgate r = sigmoid(x@Wr + h@Wr' + 0.5*(rsx+rsh) + biases)
#pragma unroll
    for (int mt = 0; mt < 2; ++mt) R4[mt] = (f32x4){0.f, 0.f, 0.f, 0.f};
    mma16(P0, WihA, col, l16, l4, R4);
    mma16(P1, WhhA, col, l16, l4, R4);
    {
      float bb = bih[a * 768 + col] + bhh[a * 768 + col];
#pragma unroll
      for (int mt = 0; mt < 2; ++mt)
#pragma unroll
        for (int r = 0; r < 4; ++r) {
          int row = mt * 16 + l4 * 4 + r;
          R4[mt][r] = sigm(R4[mt][r] + 0.5f * (RSX[row] + RSH[row]) + bb);
        }
    }

    // t = r * (h@Wn' + 0.5*rsh + bhh_n)
#pragma unroll
    for (int mt = 0; mt < 2; ++mt) T4[mt] = (f32x4){0.f, 0.f, 0.f, 0.f};
    mma16(P1, WhhA + 512 * 256, col, l16, l4, T4);
    {
      float bb = bhh[a * 768 + 512 + col];
#pragma unroll
      for (int mt = 0; mt < 2; ++mt)
#pragma unroll
        for (int r = 0; r < 4; ++r) {
          int row = mt * 16 + l4 * 4 + r;
          T4[mt][r] = R4[mt][r] * (T4[mt][r] + 0.5f * RSH[row] + bb);
        }
    }

    // newgate = tanh(x@Wn + 0.5*rsx + bih_n + t)  (G4 = ng)
#pragma unroll
    for (int mt = 0; mt < 2; ++mt) G4[mt] = (f32x4){0.f, 0.f, 0.f, 0.f};
    mma16(P0, WihA + 512 * 256, col, l16, l4, G4);
    {
      float bb = bih[a * 768 + 512 + col];
#pragma unroll
      for (int mt = 0; mt < 2; ++mt)
#pragma unroll
        for (int r = 0; r < 4; ++r) {
          int row = mt * 16 + l4 * 4 + r;
          G4[mt][r] = tanh_(G4[mt][r] + 0.5f * RSX[row] + bb + T4[mt][r]);
        }
    }

    // inputgate (reuse R4), combine, write h to global only
#pragma unroll
    for (int mt = 0; mt < 2; ++mt) R4[mt] = (f32x4){0.f, 0.f, 0.f, 0.f};
    mma16(P0, WihA + 256 * 256, col, l16, l4, R4);
    mma16(P1, WhhA + 256 * 256, col, l16, l4, R4);
    {
      float bb = bih[a * 768 + 256 + col] + bhh[a * 768 + 256 + col];
#pragma unroll
      for (int mt = 0; mt < 2; ++mt)
#pragma unroll
        for (int r = 0; r < 4; ++r) {
          int row = mt * 16 + l4 * 4 + r;
          float ig = sigm(R4[mt][r] + 0.5f * (RSX[row] + RSH[row]) + bb);
          float hv = bf2f(P1[((row << 8) + col) ^ ((row & 7) << 3)]);
          float ng = G4[mt][r];
          out[QSIZE + ((((rowbase + row) << 3) + a) << 8) + col]
              = ng + ig * (hv - ng);
        }
    }
  }
  __syncthreads();   // gates done reading P0/P1; h stores drained (vmcnt(0))

  // re-stage h (f32 in out+QSIZE, L2-hot) -> bf16 P0 for fc2
  stage_single(P0, out + QSIZE, rowbase, a, tid);
  __syncthreads();

  // ---- q = relu(h @ W2 + b2), N padded to 32; waves 0-1 cover 32 rows ----
  if (w < 2) {
    f32x4 qa[2];
    qa[0] = (f32x4){0.f, 0.f, 0.f, 0.f};
    qa[1] = (f32x4){0.f, 0.f, 0.f, 0.f};
#pragma unroll
    for (int ks = 0; ks < 8; ++ks) {
      int row = w * 16 + l16;
      int idx = ((row << 8) + ks * 32 + 8 * l4) ^ ((row & 7) << 3);
      s8 af = *(const s8*)(P0 + idx);
#pragma unroll
      for (int nt = 0; nt < 2; ++nt) {
        s8 bw = *(const s8*)(W2t + ((a * 32 + nt * 16 + l16) << 8) + ks * 32 + 8 * l4);
        qa[nt] = __builtin_amdgcn_mfma_f32_16x16x32_bf16(af, bw, qa[nt], 0, 0, 0);
      }
    }
#pragma unroll
    for (int nt = 0; nt < 2; ++nt) {
      int col = nt * 16 + l16;
      if (col < 30) {
        float bb = b2[a * 30 + col];
#pragma unroll
        for (int r = 0; r < 4; ++r) {
          int row = w * 16 + l4 * 4 + r;
          out[(((rowbase + row) << 3) + a) * 30 + col] = fmaxf(qa[nt][r] + bb, 0.f);
        }
      }
    }
  }
}

extern "C" void kernel_launch(void* const* d_in, const int* in_sizes, int n_in,
                              void* d_out, int out_size, void* d_ws, size_t ws_size,
                              hipStream_t stream) {
  const float* inputs = (const float*)d_in[0];
  const float* hidden = (const float*)d_in[1];
  const float* fc1w   = (const float*)d_in[2];
  const float* fc1b   = (const float*)d_in[3];
  const float* rihw   = (const float*)d_in[4];
  const float* rihb   = (const float*)d_in[5];
  const float* rhhw   = (const float*)d_in[6];
  const float* rhhb   = (const float*)d_in[7];
  const float* fc2w   = (const float*)d_in[8];
  const float* fc2b   = (const float*)d_in[9];
  unsigned short* ws  = (unsigned short*)d_ws;
  float* out          = (float*)d_out;

  hipLaunchKernelGGL(prep_weights, dim3(3648), dim3(256), 0, stream,
                     fc1w, rihw, rhhw, fc2w, ws);
  hipLaunchKernelGGL(fused_agent_rnn, dim3(1024), dim3(256), 0, stream,
                     inputs, hidden, fc1b, rihb, rhhb, fc2b, ws, out);
}

// Round 6
// 182.563 us; speedup vs baseline: 2.3043x; 1.0184x over previous
//
#include <hip/hip_runtime.h>

// ---------------------------------------------------------------------------
// LatentMixtureAllRNNAgent: per-agent fc1 -> GRU cell -> fc2 on MI355X.
// Round 6: 3-kernel split (fc1 / gates / fc2) to remove intra-block phase
// barriers, shrink per-kernel code (rolled nt-loop; I$ pressure) and register
// footprints. X passed K1->K2 as bf16 in ws (guarded by ws_size; fallback =
// round-5 fused kernel). h passed K2->K3 via out (f32, proven path).
// Numerics identical to rounds 2-5 (absmax 1.0): split-bf16 fc1, centered
// gate weights + exact f32 rowsum corrections, bf16 fc2.
// ---------------------------------------------------------------------------

typedef __attribute__((ext_vector_type(4))) float f32x4;
typedef __attribute__((ext_vector_type(8))) short s8;     // 8 bf16 (4 VGPRs)
typedef __attribute__((ext_vector_type(4))) unsigned short us4;
typedef __attribute__((ext_vector_type(8))) unsigned short us8;

#define QSIZE   983040      /* 32768*30 */
#define W1H_OFF 0
#define W1L_OFF 524288
#define WIH_OFF 1048576
#define WHH_OFF 2621440
#define W2T_OFF 4194304
#define XB_OFF  4259840     /* + 32768*256 ushorts = 8.39M -> ws needs 25.3MB */

static __device__ __forceinline__ unsigned short f2bf(float f) {
  union { float f; unsigned u; } v; v.f = f;
  unsigned r = v.u + 0x7FFFu + ((v.u >> 16) & 1u);   // RNE
  return (unsigned short)(r >> 16);
}
static __device__ __forceinline__ float bf2f(unsigned short u) {
  union { unsigned u; float f; } v; v.u = ((unsigned)u) << 16;
  return v.f;
}
static __device__ __forceinline__ float sigm(float x) {
  return 1.0f / (1.0f + __expf(-x));
}
static __device__ __forceinline__ float tanh_(float x) {
  return 1.0f - 2.0f / (__expf(2.0f * x) + 1.0f);
}

// ------------- prep: f32 [a][k][n] -> bf16 [a][n][k] planes in ws -----------
__global__ void prep_weights(const float* __restrict__ fc1w,
                             const float* __restrict__ rihw,
                             const float* __restrict__ rhhw,
                             const float* __restrict__ fc2w,
                             unsigned short* __restrict__ ws) {
  int q = blockIdx.x * 256 + threadIdx.x;
  if (q < 131072) {                         // fc1: hi + lo planes
    int a = q >> 14, rem = q & 16383, k4 = rem >> 8, n = rem & 255;
    const float* s = fc1w + a * 65536 + (k4 * 4) * 256 + n;
    float v0 = s[0], v1 = s[256], v2 = s[512], v3 = s[768];
    us4 hi = { f2bf(v0), f2bf(v1), f2bf(v2), f2bf(v3) };
    us4 lo = { f2bf(v0 - bf2f(hi[0])), f2bf(v1 - bf2f(hi[1])),
               f2bf(v2 - bf2f(hi[2])), f2bf(v3 - bf2f(hi[3])) };
    int o = ((a * 256 + n) << 8) + k4 * 4;
    *(us4*)(ws + W1H_OFF + o) = hi;
    *(us4*)(ws + W1L_OFF + o) = lo;
  } else if (q < 524288) {                  // rnn_ih, centered (w - 0.5)
    int t = q - 131072;
    int a = t / 49152, rem = t % 49152, k4 = rem / 768, n = rem % 768;
    const float* s = rihw + a * 196608 + (k4 * 4) * 768 + n;
    us4 v = { f2bf(s[0] - 0.5f), f2bf(s[768] - 0.5f),
              f2bf(s[1536] - 0.5f), f2bf(s[2304] - 0.5f) };
    *(us4*)(ws + WIH_OFF + ((a * 768 + n) << 8) + k4 * 4) = v;
  } else if (q < 917504) {                  // rnn_hh, centered
    int t = q - 524288;
    int a = t / 49152, rem = t % 49152, k4 = rem / 768, n = rem % 768;
    const float* s = rhhw + a * 196608 + (k4 * 4) * 768 + n;
    us4 v = { f2bf(s[0] - 0.5f), f2bf(s[768] - 0.5f),
              f2bf(s[1536] - 0.5f), f2bf(s[2304] - 0.5f) };
    *(us4*)(ws + WHH_OFF + ((a * 768 + n) << 8) + k4 * 4) = v;
  } else if (q < 933888) {                  // fc2: plain, pad 30->32
    int t = q - 917504;
    int a = t >> 11, rem = t & 2047, k4 = rem >> 5, n = rem & 31;
    us4 v = { 0, 0, 0, 0 };
    if (n < 30) {
      const float* s = fc2w + a * 7680 + (k4 * 4) * 30 + n;
      v = (us4){ f2bf(s[0]), f2bf(s[30]), f2bf(s[60]), f2bf(s[90]) };
    }
    *(us4*)(ws + W2T_OFF + ((a * 32 + n) << 8) + k4 * 4) = v;
  }
}

// ------- stage 32x256 f32 tile -> split bf16 (hi p0, lo p1), 256 thr --------
static __device__ __forceinline__ void stage_split(unsigned short* p0,
                                                   unsigned short* p1,
                                                   const float* __restrict__ src,
                                                   int rowbase, int a, int tid) {
#pragma unroll
  for (int k = 0; k < 8; ++k) {
    int j = tid + k * 256;
    int r = j >> 6;
    int c4 = (j & 63) << 2;
    const float* p = src + ((((rowbase + r) << 3) + a) << 8) + c4;
    float4 v = *(const float4*)p;
    us4 hi = { f2bf(v.x), f2bf(v.y), f2bf(v.z), f2bf(v.w) };
    us4 lo = { f2bf(v.x - bf2f(hi[0])), f2bf(v.y - bf2f(hi[1])),
               f2bf(v.z - bf2f(hi[2])), f2bf(v.w - bf2f(hi[3])) };
    int idx = ((r << 8) + c4) ^ ((r & 7) << 3);   // XOR swizzle (16B blocks)
    *(us4*)(p0 + idx) = hi;
    *(us4*)(p1 + idx) = lo;
  }
}

// ------------- stage 32x256 f32 tile -> single bf16 plane, 256 thr ----------
static __device__ __forceinline__ void stage_single(unsigned short* p,
                                                    const float* __restrict__ src,
                                                    int rowbase, int a, int tid) {
#pragma unroll
  for (int k = 0; k < 8; ++k) {
    int j = tid + k * 256;
    int r = j >> 6;
    int c4 = (j & 63) << 2;
    const float* sp = src + ((((rowbase + r) << 3) + a) << 8) + c4;
    float4 v = *(const float4*)sp;
    us4 hi = { f2bf(v.x), f2bf(v.y), f2bf(v.z), f2bf(v.w) };
    int idx = ((r << 8) + c4) ^ ((r & 7) << 3);
    *(us4*)(p + idx) = hi;
  }
}

// ---- 32x64 tile GEMM over K=256: acc[2][4] += A_lds @ Wt^T -----------------
static __device__ __forceinline__ void mma64(const unsigned short* lds,
                                             const unsigned short* __restrict__ wt,
                                             int n0, int l16, int l4,
                                             f32x4 (&acc)[2][4]) {
#pragma unroll
  for (int ks = 0; ks < 8; ++ks) {
    s8 af[2], bw[4];
#pragma unroll
    for (int mt = 0; mt < 2; ++mt) {
      int row = mt * 16 + l16;
      int idx = ((row << 8) + ks * 32 + 8 * l4) ^ ((row & 7) << 3);
      af[mt] = *(const s8*)(lds + idx);
    }
#pragma unroll
    for (int nt = 0; nt < 4; ++nt) {
      bw[nt] = *(const s8*)(wt + ((n0 + nt * 16 + l16) << 8) + ks * 32 + 8 * l4);
    }
#pragma unroll
    for (int mt = 0; mt < 2; ++mt)
#pragma unroll
      for (int nt = 0; nt < 4; ++nt)
        acc[mt][nt] = __builtin_amdgcn_mfma_f32_16x16x32_bf16(
            af[mt], bw[nt], acc[mt][nt], 0, 0, 0);
  }
}

// ---- 32x16 subtile GEMM over K=256: acc[2] += A_lds @ wt[wrow]^T -----------
static __device__ __forceinline__ void mma16(const unsigned short* lds,
                                             const unsigned short* __restrict__ wt,
                                             int wrow, int l16, int l4,
                                             f32x4 (&acc)[2]) {
#pragma unroll
  for (int ks = 0; ks < 8; ++ks) {
    s8 bw = *(const s8*)(wt + (wrow << 8) + ks * 32 + 8 * l4);
#pragma unroll
    for (int mt = 0; mt < 2; ++mt) {
      int row = mt * 16 + l16;
      int idx = ((row << 8) + ks * 32 + 8 * l4) ^ ((row & 7) << 3);
      s8 af = *(const s8*)(lds + idx);
      acc[mt] = __builtin_amdgcn_mfma_f32_16x16x32_bf16(af, bw, acc[mt], 0, 0, 0);
    }
  }
}

// ========================== K1: fc1 -> X bf16 (ws) ==========================
__global__ __launch_bounds__(256, 2) void k1_fc1(
    const float* __restrict__ inp, const float* __restrict__ b1,
    unsigned short* __restrict__ ws) {
  __shared__ __align__(16) unsigned short P0[32 * 256];
  __shared__ __align__(16) unsigned short P1[32 * 256];
  const int tid = threadIdx.x;
  const int a = blockIdx.x & 7;
  const int rowbase = (blockIdx.x >> 3) * 32;
  const int lane = tid & 63, w = tid >> 6;
  const int l16 = lane & 15, l4 = lane >> 4;
  const int n0 = w * 64;

  stage_split(P0, P1, inp, rowbase, a, tid);
  __syncthreads();

  f32x4 XA[2][4];
#pragma unroll
  for (int mt = 0; mt < 2; ++mt)
#pragma unroll
    for (int nt = 0; nt < 4; ++nt) XA[mt][nt] = (f32x4){0.f, 0.f, 0.f, 0.f};
  mma64(P0, ws + W1H_OFF + a * 65536, n0, l16, l4, XA);
  mma64(P1, ws + W1H_OFF + a * 65536, n0, l16, l4, XA);
  mma64(P0, ws + W1L_OFF + a * 65536, n0, l16, l4, XA);

  // epilogue: X = relu(. + b1) -> bf16 to ws (no barrier needed; LDS not reused)
#pragma unroll
  for (int nt = 0; nt < 4; ++nt) {
    int col = n0 + nt * 16 + l16;
    float bb = b1[a * 256 + col];
#pragma unroll
    for (int mt = 0; mt < 2; ++mt)
#pragma unroll
      for (int r = 0; r < 4; ++r) {
        float v = fmaxf(XA[mt][nt][r] + bb, 0.f);
        int row = mt * 16 + l4 * 4 + r;
        int flat = ((rowbase + row) << 3) + a;
        ws[XB_OFF + (flat << 8) + col] = f2bf(v);
      }
  }
}

// ========================== K2: gates -> h f32 (out) ========================
__global__ __launch_bounds__(256, 2) void k2_gates(
    const float* __restrict__ hin, const float* __restrict__ bih,
    const float* __restrict__ bhh, const unsigned short* __restrict__ ws,
    float* __restrict__ out) {
  __shared__ __align__(16) unsigned short P0[32 * 256];  // x (bf16)
  __shared__ __align__(16) unsigned short P1[32 * 256];  // h_in (bf16)
  __shared__ float RSXP[8][32], RSHP[8][32];
  __shared__ float RSX[32], RSH[32];

  const int tid = threadIdx.x;
  const int a = blockIdx.x & 7;
  const int rowbase = (blockIdx.x >> 3) * 32;
  const int lane = tid & 63, w = tid >> 6;
  const int l16 = lane & 15, l4 = lane >> 4;
  const int n0 = w * 64;

  // stage X (bf16 copy from ws) into P0, swizzled
#pragma unroll
  for (int k = 0; k < 4; ++k) {
    int j = tid + k * 256;                 // 0..1023 us8
    int r = j >> 5;                        // 32 us8 per row
    int c = (j & 31) << 3;
    us8 v = *(const us8*)(ws + XB_OFF + ((((rowbase + r) << 3) + a) << 8) + c);
    int idx = ((r << 8) + c) ^ ((r & 7) << 3);
    *(us8*)(P0 + idx) = v;
  }
  stage_single(P1, hin, rowbase, a, tid);
  __syncthreads();

  // exact f32 rowsums of the bf16 tiles
  {
    int row = tid >> 3, qd = tid & 7;
    float sx = 0.f, sh = 0.f;
#pragma unroll
    for (int i = 0; i < 8; ++i) {
      int c = qd * 32 + i * 4;
      int idx = ((row << 8) + c) ^ ((row & 7) << 3);
      us4 vx = *(const us4*)(P0 + idx);
      us4 vh = *(const us4*)(P1 + idx);
      sx += bf2f(vx[0]) + bf2f(vx[1]) + bf2f(vx[2]) + bf2f(vx[3]);
      sh += bf2f(vh[0]) + bf2f(vh[1]) + bf2f(vh[2]) + bf2f(vh[3]);
    }
    RSXP[qd][row] = sx; RSHP[qd][row] = sh;
  }
  __syncthreads();
  if (tid < 32) {
    float sx = 0.f, sh = 0.f;
#pragma unroll
    for (int qd = 0; qd < 8; ++qd) { sx += RSXP[qd][tid]; sh += RSHP[qd][tid]; }
    RSX[tid] = sx; RSH[tid] = sh;
  }
  __syncthreads();

  const unsigned short* WihA = ws + WIH_OFF + a * 768 * 256;
  const unsigned short* WhhA = ws + WHH_OFF + a * 768 * 256;

  for (int nt = 0; nt < 4; ++nt) {         // ROLLED: small hot loop
    const int col = n0 + nt * 16 + l16;
    f32x4 R4[2], T4[2], G4[2];

#pragma unroll
    for (int mt = 0; mt < 2; ++mt) R4[mt] = (f32x4){0.f, 0.f, 0.f, 0.f};
    mma16(P0, WihA, col, l16, l4, R4);
    mma16(P1, WhhA, col, l16, l4, R4);
    {
      float bb = bih[a * 768 + col] + bhh[a * 768 + col];
#pragma unroll
      for (int mt = 0; mt < 2; ++mt)
#pragma unroll
        for (int r = 0; r < 4; ++r) {
          int row = mt * 16 + l4 * 4 + r;
          R4[mt][r] = sigm(R4[mt][r] + 0.5f * (RSX[row] + RSH[row]) + bb);
        }
    }

#pragma unroll
    for (int mt = 0; mt < 2; ++mt) T4[mt] = (f32x4){0.f, 0.f, 0.f, 0.f};
    mma16(P1, WhhA + 512 * 256, col, l16, l4, T4);
    {
      float bb = bhh[a * 768 + 512 + col];
#pragma unroll
      for (int mt = 0; mt < 2; ++mt)
#pragma unroll
        for (int r = 0; r < 4; ++r) {
          int row = mt * 16 + l4 * 4 + r;
          T4[mt][r] = R4[mt][r] * (T4[mt][r] + 0.5f * RSH[row] + bb);
        }
    }

#pragma unroll
    for (int mt = 0; mt < 2; ++mt) G4[mt] = (f32x4){0.f, 0.f, 0.f, 0.f};
    mma16(P0, WihA + 512 * 256, col, l16, l4, G4);
    {
      float bb = bih[a * 768 + 512 + col];
#pragma unroll
      for (int mt = 0; mt < 2; ++mt)
#pragma unroll
        for (int r = 0; r < 4; ++r) {
          int row = mt * 16 + l4 * 4 + r;
          G4[mt][r] = tanh_(G4[mt][r] + 0.5f * RSX[row] + bb + T4[mt][r]);
        }
    }

#pragma unroll
    for (int mt = 0; mt < 2; ++mt) R4[mt] = (f32x4){0.f, 0.f, 0.f, 0.f};
    mma16(P0, WihA + 256 * 256, col, l16, l4, R4);
    mma16(P1, WhhA + 256 * 256, col, l16, l4, R4);
    {
      float bb = bih[a * 768 + 256 + col] + bhh[a * 768 + 256 + col];
#pragma unroll
      for (int mt = 0; mt < 2; ++mt)
#pragma unroll
        for (int r = 0; r < 4; ++r) {
          int row = mt * 16 + l4 * 4 + r;
          float ig = sigm(R4[mt][r] + 0.5f * (RSX[row] + RSH[row]) + bb);
          float hv = bf2f(P1[((row << 8) + col) ^ ((row & 7) << 3)]);
          float ng = G4[mt][r];
          out[QSIZE + ((((rowbase + row) << 3) + a) << 8) + col]
              = ng + ig * (hv - ng);
        }
    }
  }
}

// ========================== K3: fc2 -> q (out) ==============================
__global__ __launch_bounds__(128) void k3_fc2(
    const float* __restrict__ b2, const unsigned short* __restrict__ ws,
    float* __restrict__ out) {
  __shared__ __align__(16) unsigned short HB[32 * 256];
  const int tid = threadIdx.x;
  const int a = blockIdx.x & 7;
  const int rowbase = (blockIdx.x >> 3) * 32;
  const int lane = tid & 63, w = tid >> 6;     // 2 waves
  const int l16 = lane & 15, l4 = lane >> 4;

  // stage h f32 (written by K2) -> bf16 HB, swizzled (128 threads)
#pragma unroll
  for (int k = 0; k < 16; ++k) {
    int j = tid + k * 128;
    int r = j >> 6;
    int c4 = (j & 63) << 2;
    const float* sp = out + QSIZE + ((((rowbase + r) << 3) + a) << 8) + c4;
    float4 v = *(const float4*)sp;
    us4 hi = { f2bf(v.x), f2bf(v.y), f2bf(v.z), f2bf(v.w) };
    int idx = ((r << 8) + c4) ^ ((r & 7) << 3);
    *(us4*)(HB + idx) = hi;
  }
  __syncthreads();

  f32x4 qa[2];
  qa[0] = (f32x4){0.f, 0.f, 0.f, 0.f};
  qa[1] = (f32x4){0.f, 0.f, 0.f, 0.f};
#pragma unroll
  for (int ks = 0; ks < 8; ++ks) {
    int row = w * 16 + l16;
    int idx = ((row << 8) + ks * 32 + 8 * l4) ^ ((row & 7) << 3);
    s8 af = *(const s8*)(HB + idx);
#pragma unroll
    for (int nt = 0; nt < 2; ++nt) {
      s8 bw = *(const s8*)(ws + W2T_OFF + ((a * 32 + nt * 16 + l16) << 8) + ks * 32 + 8 * l4);
      qa[nt] = __builtin_amdgcn_mfma_f32_16x16x32_bf16(af, bw, qa[nt], 0, 0, 0);
    }
  }
#pragma unroll
  for (int nt = 0; nt < 2; ++nt) {
    int col = nt * 16 + l16;
    if (col < 30) {
      float bb = b2[a * 30 + col];
#pragma unroll
      for (int r = 0; r < 4; ++r) {
        int row = w * 16 + l4 * 4 + r;
        out[(((rowbase + row) << 3) + a) * 30 + col] = fmaxf(qa[nt][r] + bb, 0.f);
      }
    }
  }
}

// =================== fallback: round-5 fused kernel (proven) ================
__global__ __launch_bounds__(256, 2) void fused_agent_rnn(
    const float* __restrict__ inp,  const float* __restrict__ hin,
    const float* __restrict__ b1,   const float* __restrict__ bih,
    const float* __restrict__ bhh,  const float* __restrict__ b2,
    const unsigned short* __restrict__ ws, float* __restrict__ out) {
  __shared__ __align__(16) unsigned short P0[32 * 256];
  __shared__ __align__(16) unsigned short P1[32 * 256];
  __shared__ float RSXP[8][32], RSHP[8][32];
  __shared__ float RSX[32], RSH[32];

  const int tid = threadIdx.x;
  const int a = blockIdx.x & 7;
  const int rowbase = (blockIdx.x >> 3) * 32;
  const int lane = tid & 63, w = tid >> 6;
  const int l16 = lane & 15, l4 = lane >> 4;
  const int n0 = w * 64;

  stage_split(P0, P1, inp, rowbase, a, tid);
  __syncthreads();
  {
    f32x4 XA[2][4];
#pragma unroll
    for (int mt = 0; mt < 2; ++mt)
#pragma unroll
      for (int nt = 0; nt < 4; ++nt) XA[mt][nt] = (f32x4){0.f, 0.f, 0.f, 0.f};
    mma64(P0, ws + W1H_OFF + a * 65536, n0, l16, l4, XA);
    mma64(P1, ws + W1H_OFF + a * 65536, n0, l16, l4, XA);
    mma64(P0, ws + W1L_OFF + a * 65536, n0, l16, l4, XA);
    __syncthreads();
#pragma unroll
    for (int nt = 0; nt < 4; ++nt) {
      int col = n0 + nt * 16 + l16;
      float bb = b1[a * 256 + col];
#pragma unroll
      for (int mt = 0; mt < 2; ++mt)
#pragma unroll
        for (int r = 0; r < 4; ++r) {
          float v = fmaxf(XA[mt][nt][r] + bb, 0.f);
          int row = mt * 16 + l4 * 4 + r;
          P0[((row << 8) + col) ^ ((row & 7) << 3)] = f2bf(v);
        }
    }
  }
  stage_single(P1, hin, rowbase, a, tid);
  __syncthreads();
  {
    int row = tid >> 3, qd = tid & 7;
    float sx = 0.f, sh = 0.f;
#pragma unroll
    for (int i = 0; i < 8; ++i) {
      int c = qd * 32 + i * 4;
      int idx = ((row << 8) + c) ^ ((row & 7) << 3);
      us4 vx = *(const us4*)(P0 + idx);
      us4 vh = *(const us4*)(P1 + idx);
      sx += bf2f(vx[0]) + bf2f(vx[1]) + bf2f(vx[2]) + bf2f(vx[3]);
      sh += bf2f(vh[0]) + bf2f(vh[1]) + bf2f(vh[2]) + bf2f(vh[3]);
    }
    RSXP[qd][row] = sx; RSHP[qd][row] = sh;
  }
  __syncthreads();
  if (tid < 32) {
    float sx = 0.f, sh = 0.f;
#pragma unroll
    for (int qd = 0; qd < 8; ++qd) { sx += RSXP[qd][tid]; sh += RSHP[qd][tid]; }
    RSX[tid] = sx; RSH[tid] = sh;
  }
  __syncthreads();

  const unsigned short* WihA = ws + WIH_OFF + a * 768 * 256;
  const unsigned short* WhhA = ws + WHH_OFF + a * 768 * 256;

  for (int nt = 0; nt < 4; ++nt) {
    const int col = n0 + nt * 16 + l16;
    f32x4 R4[2], T4[2], G4[2];
#pragma unroll
    for (int mt = 0; mt < 2; ++mt) R4[mt] = (f32x4){0.f, 0.f, 0.f, 0.f};
    mma16(P0, WihA, col, l16, l4, R4);
    mma16(P1, WhhA, col, l16, l4, R4);
    {
      float bb = bih[a * 768 + col] + bhh[a * 768 + col];
#pragma unroll
      for (int mt = 0; mt < 2; ++mt)
#pragma unroll
        for (int r = 0; r < 4; ++r) {
          int row = mt * 16 + l4 * 4 + r;
          R4[mt][r] = sigm(R4[mt][r] + 0.5f * (RSX[row] + RSH[row]) + bb);
        }
    }
#pragma unroll
    for (int mt = 0; mt < 2; ++mt) T4[mt] = (f32x4){0.f, 0.f, 0.f, 0.f};
    mma16(P1, WhhA + 512 * 256, col, l16, l4, T4);
    {
      float bb = bhh[a * 768 + 512 + col];
#pragma unroll
      for (int mt = 0; mt < 2; ++mt)
#pragma unroll
        for (int r = 0; r < 4; ++r) {
          int row = mt * 16 + l4 * 4 + r;
          T4[mt][r] = R4[mt][r] * (T4[mt][r] + 0.5f * RSH[row] + bb);
        }
    }
#pragma unroll
    for (int mt = 0; mt < 2; ++mt) G4[mt] = (f32x4){0.f, 0.f, 0.f, 0.f};
    mma16(P0, WihA + 512 * 256, col, l16, l4, G4);
    {
      float bb = bih[a * 768 + 512 + col];
#pragma unroll
      for (int mt = 0; mt < 2; ++mt)
#pragma unroll
        for (int r = 0; r < 4; ++r) {
          int row = mt * 16 + l4 * 4 + r;
          G4[mt][r] = tanh_(G4[mt][r] + 0.5f * RSX[row] + bb + T4[mt][r]);
        }
    }
#pragma unroll
    for (int mt = 0; mt < 2; ++mt) R4[mt] = (f32x4){0.f, 0.f, 0.f, 0.f};
    mma16(P0, WihA + 256 * 256, col, l16, l4, R4);
    mma16(P1, WhhA + 256 * 256, col, l16, l4, R4);
    {
      float bb = bih[a * 768 + 256 + col] + bhh[a * 768 + 256 + col];
#pragma unroll
      for (int mt = 0; mt < 2; ++mt)
#pragma unroll
        for (int r = 0; r < 4; ++r) {
          int row = mt * 16 + l4 * 4 + r;
          float ig = sigm(R4[mt][r] + 0.5f * (RSX[row] + RSH[row]) + bb);
          float hv = bf2f(P1[((row << 8) + col) ^ ((row & 7) << 3)]);
          float ng = G4[mt][r];
          out[QSIZE + ((((rowbase + row) << 3) + a) << 8) + col]
              = ng + ig * (hv - ng);
        }
    }
  }
  __syncthreads();
  stage_single(P0, out + QSIZE, rowbase, a, tid);
  __syncthreads();
  if (w < 2) {
    f32x4 qa[2];
    qa[0] = (f32x4){0.f, 0.f, 0.f, 0.f};
    qa[1] = (f32x4){0.f, 0.f, 0.f, 0.f};
#pragma unroll
    for (int ks = 0; ks < 8; ++ks) {
      int row = w * 16 + l16;
      int idx = ((row << 8) + ks * 32 + 8 * l4) ^ ((row & 7) << 3);
      s8 af = *(const s8*)(P0 + idx);
#pragma unroll
      for (int nt = 0; nt < 2; ++nt) {
        s8 bw = *(const s8*)(ws + W2T_OFF + ((a * 32 + nt * 16 + l16) << 8) + ks * 32 + 8 * l4);
        qa[nt] = __builtin_amdgcn_mfma_f32_16x16x32_bf16(af, bw, qa[nt], 0, 0, 0);
      }
    }
#pragma unroll
    for (int nt = 0; nt < 2; ++nt) {
      int col = nt * 16 + l16;
      if (col < 30) {
        float bb = b2[a * 30 + col];
#pragma unroll
        for (int r = 0; r < 4; ++r) {
          int row = w * 16 + l4 * 4 + r;
          out[(((rowbase + row) << 3) + a) * 30 + col] = fmaxf(qa[nt][r] + bb, 0.f);
        }
      }
    }
  }
}

extern "C" void kernel_launch(void* const* d_in, const int* in_sizes, int n_in,
                              void* d_out, int out_size, void* d_ws, size_t ws_size,
                              hipStream_t stream) {
  const float* inputs = (const float*)d_in[0];
  const float* hidden = (const float*)d_in[1];
  const float* fc1w   = (const float*)d_in[2];
  const float* fc1b   = (const float*)d_in[3];
  const float* rihw   = (const float*)d_in[4];
  const float* rihb   = (const float*)d_in[5];
  const float* rhhw   = (const float*)d_in[6];
  const float* rhhb   = (const float*)d_in[7];
  const float* fc2w   = (const float*)d_in[8];
  const float* fc2b   = (const float*)d_in[9];
  unsigned short* ws  = (unsigned short*)d_ws;
  float* out          = (float*)d_out;

  hipLaunchKernelGGL(prep_weights, dim3(3648), dim3(256), 0, stream,
                     fc1w, rihw, rhhw, fc2w, ws);

  const size_t need = (size_t)(XB_OFF + 32768 * 256) * 2;   // 25.3 MB
  if (ws_size >= need) {
    hipLaunchKernelGGL(k1_fc1,  dim3(1024), dim3(256), 0, stream, inputs, fc1b, ws);
    hipLaunchKernelGGL(k2_gates, dim3(1024), dim3(256), 0, stream,
                       hidden, rihb, rhhb, ws, out);
    hipLaunchKernelGGL(k3_fc2,  dim3(1024), dim3(128), 0, stream, fc2b, ws, out);
  } else {
    hipLaunchKernelGGL(fused_agent_rnn, dim3(1024), dim3(256), 0, stream,
                       inputs, hidden, fc1b, rihb, rhhb, fc2b, ws, out);
  }
}

// Round 7
// 181.137 us; speedup vs baseline: 2.3225x; 1.0079x over previous
//
#include <hip/hip_runtime.h>

// ---------------------------------------------------------------------------
// LatentMixtureAllRNNAgent: per-agent fc1 -> GRU cell -> fc2 on MI355X.
// Round 7: k2_gates rewritten WIDE (mma64, 64-col per wave) with register
// reuse so only two [2][4] f32x4 arrays are ever live (R, T). Round-6 k2 was
// latency-serialized by the narrow mma16 shape (1 weight load : 2 MFMA, 2-way
// ILP). Wide = 4 independent loads/ks + 8 independent acc chains.
// Numerics identical to rounds 2-6 (absmax 1.0).
// ---------------------------------------------------------------------------

typedef __attribute__((ext_vector_type(4))) float f32x4;
typedef __attribute__((ext_vector_type(8))) short s8;     // 8 bf16 (4 VGPRs)
typedef __attribute__((ext_vector_type(4))) unsigned short us4;
typedef __attribute__((ext_vector_type(8))) unsigned short us8;

#define QSIZE   983040      /* 32768*30 */
#define W1H_OFF 0
#define W1L_OFF 524288
#define WIH_OFF 1048576
#define WHH_OFF 2621440
#define W2T_OFF 4194304
#define XB_OFF  4259840     /* + 32768*256 ushorts -> ws needs 25.3MB */

static __device__ __forceinline__ unsigned short f2bf(float f) {
  union { float f; unsigned u; } v; v.f = f;
  unsigned r = v.u + 0x7FFFu + ((v.u >> 16) & 1u);   // RNE
  return (unsigned short)(r >> 16);
}
static __device__ __forceinline__ float bf2f(unsigned short u) {
  union { unsigned u; float f; } v; v.u = ((unsigned)u) << 16;
  return v.f;
}
static __device__ __forceinline__ float sigm(float x) {
  return 1.0f / (1.0f + __expf(-x));
}
static __device__ __forceinline__ float tanh_(float x) {
  return 1.0f - 2.0f / (__expf(2.0f * x) + 1.0f);
}

// ------------- prep: f32 [a][k][n] -> bf16 [a][n][k] planes in ws -----------
__global__ void prep_weights(const float* __restrict__ fc1w,
                             const float* __restrict__ rihw,
                             const float* __restrict__ rhhw,
                             const float* __restrict__ fc2w,
                             unsigned short* __restrict__ ws) {
  int q = blockIdx.x * 256 + threadIdx.x;
  if (q < 131072) {                         // fc1: hi + lo planes
    int a = q >> 14, rem = q & 16383, k4 = rem >> 8, n = rem & 255;
    const float* s = fc1w + a * 65536 + (k4 * 4) * 256 + n;
    float v0 = s[0], v1 = s[256], v2 = s[512], v3 = s[768];
    us4 hi = { f2bf(v0), f2bf(v1), f2bf(v2), f2bf(v3) };
    us4 lo = { f2bf(v0 - bf2f(hi[0])), f2bf(v1 - bf2f(hi[1])),
               f2bf(v2 - bf2f(hi[2])), f2bf(v3 - bf2f(hi[3])) };
    int o = ((a * 256 + n) << 8) + k4 * 4;
    *(us4*)(ws + W1H_OFF + o) = hi;
    *(us4*)(ws + W1L_OFF + o) = lo;
  } else if (q < 524288) {                  // rnn_ih, centered (w - 0.5)
    int t = q - 131072;
    int a = t / 49152, rem = t % 49152, k4 = rem / 768, n = rem % 768;
    const float* s = rihw + a * 196608 + (k4 * 4) * 768 + n;
    us4 v = { f2bf(s[0] - 0.5f), f2bf(s[768] - 0.5f),
              f2bf(s[1536] - 0.5f), f2bf(s[2304] - 0.5f) };
    *(us4*)(ws + WIH_OFF + ((a * 768 + n) << 8) + k4 * 4) = v;
  } else if (q < 917504) {                  // rnn_hh, centered
    int t = q - 524288;
    int a = t / 49152, rem = t % 49152, k4 = rem / 768, n = rem % 768;
    const float* s = rhhw + a * 196608 + (k4 * 4) * 768 + n;
    us4 v = { f2bf(s[0] - 0.5f), f2bf(s[768] - 0.5f),
              f2bf(s[1536] - 0.5f), f2bf(s[2304] - 0.5f) };
    *(us4*)(ws + WHH_OFF + ((a * 768 + n) << 8) + k4 * 4) = v;
  } else if (q < 933888) {                  // fc2: plain, pad 30->32
    int t = q - 917504;
    int a = t >> 11, rem = t & 2047, k4 = rem >> 5, n = rem & 31;
    us4 v = { 0, 0, 0, 0 };
    if (n < 30) {
      const float* s = fc2w + a * 7680 + (k4 * 4) * 30 + n;
      v = (us4){ f2bf(s[0]), f2bf(s[30]), f2bf(s[60]), f2bf(s[90]) };
    }
    *(us4*)(ws + W2T_OFF + ((a * 32 + n) << 8) + k4 * 4) = v;
  }
}

// ------- stage 32x256 f32 tile -> split bf16 (hi p0, lo p1), 256 thr --------
static __device__ __forceinline__ void stage_split(unsigned short* p0,
                                                   unsigned short* p1,
                                                   const float* __restrict__ src,
                                                   int rowbase, int a, int tid) {
#pragma unroll
  for (int k = 0; k < 8; ++k) {
    int j = tid + k * 256;
    int r = j >> 6;
    int c4 = (j & 63) << 2;
    const float* p = src + ((((rowbase + r) << 3) + a) << 8) + c4;
    float4 v = *(const float4*)p;
    us4 hi = { f2bf(v.x), f2bf(v.y), f2bf(v.z), f2bf(v.w) };
    us4 lo = { f2bf(v.x - bf2f(hi[0])), f2bf(v.y - bf2f(hi[1])),
               f2bf(v.z - bf2f(hi[2])), f2bf(v.w - bf2f(hi[3])) };
    int idx = ((r << 8) + c4) ^ ((r & 7) << 3);   // XOR swizzle (16B blocks)
    *(us4*)(p0 + idx) = hi;
    *(us4*)(p1 + idx) = lo;
  }
}

// ------------- stage 32x256 f32 tile -> single bf16 plane, 256 thr ----------
static __device__ __forceinline__ void stage_single(unsigned short* p,
                                                    const float* __restrict__ src,
                                                    int rowbase, int a, int tid) {
#pragma unroll
  for (int k = 0; k < 8; ++k) {
    int j = tid + k * 256;
    int r = j >> 6;
    int c4 = (j & 63) << 2;
    const float* sp = src + ((((rowbase + r) << 3) + a) << 8) + c4;
    float4 v = *(const float4*)sp;
    us4 hi = { f2bf(v.x), f2bf(v.y), f2bf(v.z), f2bf(v.w) };
    int idx = ((r << 8) + c4) ^ ((r & 7) << 3);
    *(us4*)(p + idx) = hi;
  }
}

// ---- 32x64 tile GEMM over K=256: acc[2][4] += A_lds @ Wt^T -----------------
static __device__ __forceinline__ void mma64(const unsigned short* lds,
                                             const unsigned short* __restrict__ wt,
                                             int n0, int l16, int l4,
                                             f32x4 (&acc)[2][4]) {
#pragma unroll
  for (int ks = 0; ks < 8; ++ks) {
    s8 af[2], bw[4];
#pragma unroll
    for (int mt = 0; mt < 2; ++mt) {
      int row = mt * 16 + l16;
      int idx = ((row << 8) + ks * 32 + 8 * l4) ^ ((row & 7) << 3);
      af[mt] = *(const s8*)(lds + idx);
    }
#pragma unroll
    for (int nt = 0; nt < 4; ++nt) {
      bw[nt] = *(const s8*)(wt + ((n0 + nt * 16 + l16) << 8) + ks * 32 + 8 * l4);
    }
#pragma unroll
    for (int mt = 0; mt < 2; ++mt)
#pragma unroll
      for (int nt = 0; nt < 4; ++nt)
        acc[mt][nt] = __builtin_amdgcn_mfma_f32_16x16x32_bf16(
            af[mt], bw[nt], acc[mt][nt], 0, 0, 0);
  }
}

// ---- 32x16 subtile GEMM over K=256 (fallback kernel only) ------------------
static __device__ __forceinline__ void mma16(const unsigned short* lds,
                                             const unsigned short* __restrict__ wt,
                                             int wrow, int l16, int l4,
                                             f32x4 (&acc)[2]) {
#pragma unroll
  for (int ks = 0; ks < 8; ++ks) {
    s8 bw = *(const s8*)(wt + (wrow << 8) + ks * 32 + 8 * l4);
#pragma unroll
    for (int mt = 0; mt < 2; ++mt) {
      int row = mt * 16 + l16;
      int idx = ((row << 8) + ks * 32 + 8 * l4) ^ ((row & 7) << 3);
      s8 af = *(const s8*)(lds + idx);
      acc[mt] = __builtin_amdgcn_mfma_f32_16x16x32_bf16(af, bw, acc[mt], 0, 0, 0);
    }
  }
}

// ========================== K1: fc1 -> X bf16 (ws) ==========================
__global__ __launch_bounds__(256, 2) void k1_fc1(
    const float* __restrict__ inp, const float* __restrict__ b1,
    unsigned short* __restrict__ ws) {
  __shared__ __align__(16) unsigned short P0[32 * 256];
  __shared__ __align__(16) unsigned short P1[32 * 256];
  const int tid = threadIdx.x;
  const int a = blockIdx.x & 7;
  const int rowbase = (blockIdx.x >> 3) * 32;
  const int lane = tid & 63, w = tid >> 6;
  const int l16 = lane & 15, l4 = lane >> 4;
  const int n0 = w * 64;

  stage_split(P0, P1, inp, rowbase, a, tid);
  __syncthreads();

  f32x4 XA[2][4];
#pragma unroll
  for (int mt = 0; mt < 2; ++mt)
#pragma unroll
    for (int nt = 0; nt < 4; ++nt) XA[mt][nt] = (f32x4){0.f, 0.f, 0.f, 0.f};
  mma64(P0, ws + W1H_OFF + a * 65536, n0, l16, l4, XA);
  mma64(P1, ws + W1H_OFF + a * 65536, n0, l16, l4, XA);
  mma64(P0, ws + W1L_OFF + a * 65536, n0, l16, l4, XA);

#pragma unroll
  for (int nt = 0; nt < 4; ++nt) {
    int col = n0 + nt * 16 + l16;
    float bb = b1[a * 256 + col];
#pragma unroll
    for (int mt = 0; mt < 2; ++mt)
#pragma unroll
      for (int r = 0; r < 4; ++r) {
        float v = fmaxf(XA[mt][nt][r] + bb, 0.f);
        int row = mt * 16 + l4 * 4 + r;
        int flat = ((rowbase + row) << 3) + a;
        ws[XB_OFF + (flat << 8) + col] = f2bf(v);
      }
  }
}

// ========================== K2: gates -> h f32 (out), WIDE ==================
__global__ __launch_bounds__(256, 1) void k2_gates(
    const float* __restrict__ hin, const float* __restrict__ bih,
    const float* __restrict__ bhh, const unsigned short* __restrict__ ws,
    float* __restrict__ out) {
  __shared__ __align__(16) unsigned short P0[32 * 256];  // x (bf16)
  __shared__ __align__(16) unsigned short P1[32 * 256];  // h_in (bf16)
  __shared__ float RSXP[8][32], RSHP[8][32];
  __shared__ float RSX[32], RSH[32];

  const int tid = threadIdx.x;
  const int a = blockIdx.x & 7;
  const int rowbase = (blockIdx.x >> 3) * 32;
  const int lane = tid & 63, w = tid >> 6;
  const int l16 = lane & 15, l4 = lane >> 4;
  const int n0 = w * 64;

  // stage X (bf16 copy from ws) into P0, swizzled
#pragma unroll
  for (int k = 0; k < 4; ++k) {
    int j = tid + k * 256;
    int r = j >> 5;
    int c = (j & 31) << 3;
    us8 v = *(const us8*)(ws + XB_OFF + ((((rowbase + r) << 3) + a) << 8) + c);
    int idx = ((r << 8) + c) ^ ((r & 7) << 3);
    *(us8*)(P0 + idx) = v;
  }
  stage_single(P1, hin, rowbase, a, tid);
  __syncthreads();

  // exact f32 rowsums of the bf16 tiles
  {
    int row = tid >> 3, qd = tid & 7;
    float sx = 0.f, sh = 0.f;
#pragma unroll
    for (int i = 0; i < 8; ++i) {
      int c = qd * 32 + i * 4;
      int idx = ((row << 8) + c) ^ ((row & 7) << 3);
      us4 vx = *(const us4*)(P0 + idx);
      us4 vh = *(const us4*)(P1 + idx);
      sx += bf2f(vx[0]) + bf2f(vx[1]) + bf2f(vx[2]) + bf2f(vx[3]);
      sh += bf2f(vh[0]) + bf2f(vh[1]) + bf2f(vh[2]) + bf2f(vh[3]);
    }
    RSXP[qd][row] = sx; RSHP[qd][row] = sh;
  }
  __syncthreads();
  if (tid < 32) {
    float sx = 0.f, sh = 0.f;
#pragma unroll
    for (int qd = 0; qd < 8; ++qd) { sx += RSXP[qd][tid]; sh += RSHP[qd][tid]; }
    RSX[tid] = sx; RSH[tid] = sh;
  }
  __syncthreads();

  const unsigned short* WihA = ws + WIH_OFF + a * 768 * 256;
  const unsigned short* WhhA = ws + WHH_OFF + a * 768 * 256;

  // Only two wide arrays ever live: R and T (64 f32 total).
  f32x4 R[2][4], T[2][4];

  // ---- R = sigmoid(x@Wr + h@Wr' + 0.5*(rsx+rsh) + biases) ----
#pragma unroll
  for (int mt = 0; mt < 2; ++mt)
#pragma unroll
    for (int nt = 0; nt < 4; ++nt) R[mt][nt] = (f32x4){0.f, 0.f, 0.f, 0.f};
  mma64(P0, WihA, n0, l16, l4, R);
  mma64(P1, WhhA, n0, l16, l4, R);
#pragma unroll
  for (int nt = 0; nt < 4; ++nt) {
    int col = n0 + nt * 16 + l16;
    float bb = bih[a * 768 + col] + bhh[a * 768 + col];
#pragma unroll
    for (int mt = 0; mt < 2; ++mt)
#pragma unroll
      for (int r = 0; r < 4; ++r) {
        int row = mt * 16 + l4 * 4 + r;
        R[mt][nt][r] = sigm(R[mt][nt][r] + 0.5f * (RSX[row] + RSH[row]) + bb);
      }
  }

  // ---- T = r * (h@Wn' + 0.5*rsh + bhh_n) ----
#pragma unroll
  for (int mt = 0; mt < 2; ++mt)
#pragma unroll
    for (int nt = 0; nt < 4; ++nt) T[mt][nt] = (f32x4){0.f, 0.f, 0.f, 0.f};
  mma64(P1, WhhA + 512 * 256, n0, l16, l4, T);
#pragma unroll
  for (int nt = 0; nt < 4; ++nt) {
    int col = n0 + nt * 16 + l16;
    float bb = bhh[a * 768 + 512 + col];
#pragma unroll
    for (int mt = 0; mt < 2; ++mt)
#pragma unroll
      for (int r = 0; r < 4; ++r) {
        int row = mt * 16 + l4 * 4 + r;
        T[mt][nt][r] = R[mt][nt][r] * (T[mt][nt][r] + 0.5f * RSH[row] + bb);
      }
  }

  // ---- newgate (reuse R as acc): T <- tanh(x@Wn + 0.5*rsx + bih_n + T) ----
#pragma unroll
  for (int mt = 0; mt < 2; ++mt)
#pragma unroll
    for (int nt = 0; nt < 4; ++nt) R[mt][nt] = (f32x4){0.f, 0.f, 0.f, 0.f};
  mma64(P0, WihA + 512 * 256, n0, l16, l4, R);
#pragma unroll
  for (int nt = 0; nt < 4; ++nt) {
    int col = n0 + nt * 16 + l16;
    float bb = bih[a * 768 + 512 + col];
#pragma unroll
    for (int mt = 0; mt < 2; ++mt)
#pragma unroll
      for (int r = 0; r < 4; ++r) {
        int row = mt * 16 + l4 * 4 + r;
        T[mt][nt][r] = tanh_(R[mt][nt][r] + 0.5f * RSX[row] + bb + T[mt][nt][r]);
      }
  }

  // ---- inputgate (reuse R as acc), combine, write h ----
#pragma unroll
  for (int mt = 0; mt < 2; ++mt)
#pragma unroll
    for (int nt = 0; nt < 4; ++nt) R[mt][nt] = (f32x4){0.f, 0.f, 0.f, 0.f};
  mma64(P0, WihA + 256 * 256, n0, l16, l4, R);
  mma64(P1, WhhA + 256 * 256, n0, l16, l4, R);
#pragma unroll
  for (int nt = 0; nt < 4; ++nt) {
    int col = n0 + nt * 16 + l16;
    float bb = bih[a * 768 + 256 + col] + bhh[a * 768 + 256 + col];
#pragma unroll
    for (int mt = 0; mt < 2; ++mt)
#pragma unroll
      for (int r = 0; r < 4; ++r) {
        int row = mt * 16 + l4 * 4 + r;
        float ig = sigm(R[mt][nt][r] + 0.5f * (RSX[row] + RSH[row]) + bb);
        float hv = bf2f(P1[((row << 8) + col) ^ ((row & 7) << 3)]);
        float ng = T[mt][nt][r];
        out[QSIZE + ((((rowbase + row) << 3) + a) << 8) + col]
            = ng + ig * (hv - ng);
      }
  }
}

// ========================== K3: fc2 -> q (out) ==============================
__global__ __launch_bounds__(128) void k3_fc2(
    const float* __restrict__ b2, const unsigned short* __restrict__ ws,
    float* __restrict__ out) {
  __shared__ __align__(16) unsigned short HB[32 * 256];
  const int tid = threadIdx.x;
  const int a = blockIdx.x & 7;
  const int rowbase = (blockIdx.x >> 3) * 32;
  const int lane = tid & 63, w = tid >> 6;     // 2 waves
  const int l16 = lane & 15, l4 = lane >> 4;

#pragma unroll
  for (int k = 0; k < 16; ++k) {
    int j = tid + k * 128;
    int r = j >> 6;
    int c4 = (j & 63) << 2;
    const float* sp = out + QSIZE + ((((rowbase + r) << 3) + a) << 8) + c4;
    float4 v = *(const float4*)sp;
    us4 hi = { f2bf(v.x), f2bf(v.y), f2bf(v.z), f2bf(v.w) };
    int idx = ((r << 8) + c4) ^ ((r & 7) << 3);
    *(us4*)(HB + idx) = hi;
  }
  __syncthreads();

  f32x4 qa[2];
  qa[0] = (f32x4){0.f, 0.f, 0.f, 0.f};
  qa[1] = (f32x4){0.f, 0.f, 0.f, 0.f};
#pragma unroll
  for (int ks = 0; ks < 8; ++ks) {
    int row = w * 16 + l16;
    int idx = ((row << 8) + ks * 32 + 8 * l4) ^ ((row & 7) << 3);
    s8 af = *(const s8*)(HB + idx);
#pragma unroll
    for (int nt = 0; nt < 2; ++nt) {
      s8 bw = *(const s8*)(ws + W2T_OFF + ((a * 32 + nt * 16 + l16) << 8) + ks * 32 + 8 * l4);
      qa[nt] = __builtin_amdgcn_mfma_f32_16x16x32_bf16(af, bw, qa[nt], 0, 0, 0);
    }
  }
#pragma unroll
  for (int nt = 0; nt < 2; ++nt) {
    int col = nt * 16 + l16;
    if (col < 30) {
      float bb = b2[a * 30 + col];
#pragma unroll
      for (int r = 0; r < 4; ++r) {
        int row = w * 16 + l4 * 4 + r;
        out[(((rowbase + row) << 3) + a) * 30 + col] = fmaxf(qa[nt][r] + bb, 0.f);
      }
    }
  }
}

// =================== fallback: round-5 fused kernel (proven) ================
__global__ __launch_bounds__(256, 2) void fused_agent_rnn(
    const float* __restrict__ inp,  const float* __restrict__ hin,
    const float* __restrict__ b1,   const float* __restrict__ bih,
    const float* __restrict__ bhh,  const float* __restrict__ b2,
    const unsigned short* __restrict__ ws, float* __restrict__ out) {
  __shared__ __align__(16) unsigned short P0[32 * 256];
  __shared__ __align__(16) unsigned short P1[32 * 256];
  __shared__ float RSXP[8][32], RSHP[8][32];
  __shared__ float RSX[32], RSH[32];

  const int tid = threadIdx.x;
  const int a = blockIdx.x & 7;
  const int rowbase = (blockIdx.x >> 3) * 32;
  const int lane = tid & 63, w = tid >> 6;
  const int l16 = lane & 15, l4 = lane >> 4;
  const int n0 = w * 64;

  stage_split(P0, P1, inp, rowbase, a, tid);
  __syncthreads();
  {
    f32x4 XA[2][4];
#pragma unroll
    for (int mt = 0; mt < 2; ++mt)
#pragma unroll
      for (int nt = 0; nt < 4; ++nt) XA[mt][nt] = (f32x4){0.f, 0.f, 0.f, 0.f};
    mma64(P0, ws + W1H_OFF + a * 65536, n0, l16, l4, XA);
    mma64(P1, ws + W1H_OFF + a * 65536, n0, l16, l4, XA);
    mma64(P0, ws + W1L_OFF + a * 65536, n0, l16, l4, XA);
    __syncthreads();
#pragma unroll
    for (int nt = 0; nt < 4; ++nt) {
      int col = n0 + nt * 16 + l16;
      float bb = b1[a * 256 + col];
#pragma unroll
      for (int mt = 0; mt < 2; ++mt)
#pragma unroll
        for (int r = 0; r < 4; ++r) {
          float v = fmaxf(XA[mt][nt][r] + bb, 0.f);
          int row = mt * 16 + l4 * 4 + r;
          P0[((row << 8) + col) ^ ((row & 7) << 3)] = f2bf(v);
        }
    }
  }
  stage_single(P1, hin, rowbase, a, tid);
  __syncthreads();
  {
    int row = tid >> 3, qd = tid & 7;
    float sx = 0.f, sh = 0.f;
#pragma unroll
    for (int i = 0; i < 8; ++i) {
      int c = qd * 32 + i * 4;
      int idx = ((row << 8) + c) ^ ((row & 7) << 3);
      us4 vx = *(const us4*)(P0 + idx);
      us4 vh = *(const us4*)(P1 + idx);
      sx += bf2f(vx[0]) + bf2f(vx[1]) + bf2f(vx[2]) + bf2f(vx[3]);
      sh += bf2f(vh[0]) + bf2f(vh[1]) + bf2f(vh[2]) + bf2f(vh[3]);
    }
    RSXP[qd][row] = sx; RSHP[qd][row] = sh;
  }
  __syncthreads();
  if (tid < 32) {
    float sx = 0.f, sh = 0.f;
#pragma unroll
    for (int qd = 0; qd < 8; ++qd) { sx += RSXP[qd][tid]; sh += RSHP[qd][tid]; }
    RSX[tid] = sx; RSH[tid] = sh;
  }
  __syncthreads();

  const unsigned short* WihA = ws + WIH_OFF + a * 768 * 256;
  const unsigned short* WhhA = ws + WHH_OFF + a * 768 * 256;

  for (int nt = 0; nt < 4; ++nt) {
    const int col = n0 + nt * 16 + l16;
    f32x4 R4[2], T4[2], G4[2];
#pragma unroll
    for (int mt = 0; mt < 2; ++mt) R4[mt] = (f32x4){0.f, 0.f, 0.f, 0.f};
    mma16(P0, WihA, col, l16, l4, R4);
    mma16(P1, WhhA, col, l16, l4, R4);
    {
      float bb = bih[a * 768 + col] + bhh[a * 768 + col];
#pragma unroll
      for (int mt = 0; mt < 2; ++mt)
#pragma unroll
        for (int r = 0; r < 4; ++r) {
          int row = mt * 16 + l4 * 4 + r;
          R4[mt][r] = sigm(R4[mt][r] + 0.5f * (RSX[row] + RSH[row]) + bb);
        }
    }
#pragma unroll
    for (int mt = 0; mt < 2; ++mt) T4[mt] = (f32x4){0.f, 0.f, 0.f, 0.f};
    mma16(P1, WhhA + 512 * 256, col, l16, l4, T4);
    {
      float bb = bhh[a * 768 + 512 + col];
#pragma unroll
      for (int mt = 0; mt < 2; ++mt)
#pragma unroll
        for (int r = 0; r < 4; ++r) {
          int row = mt * 16 + l4 * 4 + r;
          T4[mt][r] = R4[mt][r] * (T4[mt][r] + 0.5f * RSH[row] + bb);
        }
    }
#pragma unroll
    for (int mt = 0; mt < 2; ++mt) G4[mt] = (f32x4){0.f, 0.f, 0.f, 0.f};
    mma16(P0, WihA + 512 * 256, col, l16, l4, G4);
    {
      float bb = bih[a * 768 + 512 + col];
#pragma unroll
      for (int mt = 0; mt < 2; ++mt)
#pragma unroll
        for (int r = 0; r < 4; ++r) {
          int row = mt * 16 + l4 * 4 + r;
          G4[mt][r] = tanh_(G4[mt][r] + 0.5f * RSX[row] + bb + T4[mt][r]);
        }
    }
#pragma unroll
    for (int mt = 0; mt < 2; ++mt) R4[mt] = (f32x4){0.f, 0.f, 0.f, 0.f};
    mma16(P0, WihA + 256 * 256, col, l16, l4, R4);
    mma16(P1, WhhA + 256 * 256, col, l16, l4, R4);
    {
      float bb = bih[a * 768 + 256 + col] + bhh[a * 768 + 256 + col];
#pragma unroll
      for (int mt = 0; mt < 2; ++mt)
#pragma unroll
        for (int r = 0; r < 4; ++r) {
          int row = mt * 16 + l4 * 4 + r;
          float ig = sigm(R4[mt][r] + 0.5f * (RSX[row] + RSH[row]) + bb);
          float hv = bf2f(P1[((row << 8) + col) ^ ((row & 7) << 3)]);
          float ng = G4[mt][r];
          out[QSIZE + ((((rowbase + row) << 3) + a) << 8) + col]
              = ng + ig * (hv - ng);
        }
    }
  }
  __syncthreads();
  stage_single(P0, out + QSIZE, rowbase, a, tid);
  __syncthreads();
  if (w < 2) {
    f32x4 qa[2];
    qa[0] = (f32x4){0.f, 0.f, 0.f, 0.f};
    qa[1] = (f32x4){0.f, 0.f, 0.f, 0.f};
#pragma unroll
    for (int ks = 0; ks < 8; ++ks) {
      int row = w * 16 + l16;
      int idx = ((row << 8) + ks * 32 + 8 * l4) ^ ((row & 7) << 3);
      s8 af = *(const s8*)(P0 + idx);
#pragma unroll
      for (int nt = 0; nt < 2; ++nt) {
        s8 bw = *(const s8*)(ws + W2T_OFF + ((a * 32 + nt * 16 + l16) << 8) + ks * 32 + 8 * l4);
        qa[nt] = __builtin_amdgcn_mfma_f32_16x16x32_bf16(af, bw, qa[nt], 0, 0, 0);
      }
    }
#pragma unroll
    for (int nt = 0; nt < 2; ++nt) {
      int col = nt * 16 + l16;
      if (col < 30) {
        float bb = b2[a * 30 + col];
#pragma unroll
        for (int r = 0; r < 4; ++r) {
          int row = w * 16 + l4 * 4 + r;
          out[(((rowbase + row) << 3) + a) * 30 + col] = fmaxf(qa[nt][r] + bb, 0.f);
        }
      }
    }
  }
}

extern "C" void kernel_launch(void* const* d_in, const int* in_sizes, int n_in,
                              void* d_out, int out_size, void* d_ws, size_t ws_size,
                              hipStream_t stream) {
  const float* inputs = (const float*)d_in[0];
  const float* hidden = (const float*)d_in[1];
  const float* fc1w   = (const float*)d_in[2];
  const float* fc1b   = (const float*)d_in[3];
  const float* rihw   = (const float*)d_in[4];
  const float* rihb   = (const float*)d_in[5];
  const float* rhhw   = (const float*)d_in[6];
  const float* rhhb   = (const float*)d_in[7];
  const float* fc2w   = (const float*)d_in[8];
  const float* fc2b   = (const float*)d_in[9];
  unsigned short* ws  = (unsigned short*)d_ws;
  float* out          = (float*)d_out;

  hipLaunchKernelGGL(prep_weights, dim3(3648), dim3(256), 0, stream,
                     fc1w, rihw, rhhw, fc2w, ws);

  const size_t need = (size_t)(XB_OFF + 32768 * 256) * 2;   // 25.3 MB
  if (ws_size >= need) {
    hipLaunchKernelGGL(k1_fc1,  dim3(1024), dim3(256), 0, stream, inputs, fc1b, ws);
    hipLaunchKernelGGL(k2_gates, dim3(1024), dim3(256), 0, stream,
                       hidden, rihb, rhhb, ws, out);
    hipLaunchKernelGGL(k3_fc2,  dim3(1024), dim3(128), 0, stream, fc2b, ws, out);
  } else {
    hipLaunchKernelGGL(fused_agent_rnn, dim3(1024), dim3(256), 0, stream,
                       inputs, hidden, fc1b, rihb, rhhb, fc2b, ws, out);
  }
}